// Round 3
// baseline (6185.901 us; speedup 1.0000x reference)
//
#include <hip/hip_runtime.h>

// ---------------------------------------------------------------------------
// Elastic 2D velocity-stress staggered FD + C-PML, 2 shots, 128 steps.
// Round 3: persistent cooperative kernel (R2 design), fence spelling fixed
// (__threadfence instead of the nonexistent __hip_atomic_fence).
//  - 256 blocks = 2 shots x (4 x-tiles x 32 y-tiles); velocities computed
//    redundantly on a +2 halo into LDS so the stress phase is block-local.
//  - Double-buffered: vy,vx, stresses, velocity-phase CPML memories (cross-
//    block same-phase readers exist). Stress-phase memories owner-private.
//  - Hand-rolled sense-reversing grid barrier w/ device-scope fences.
//  - Fallback to round-1 multi-launch path if ws_size too small.
// ---------------------------------------------------------------------------

#define NYI   300
#define NXI   300
#define PML   20
#define NYP   340
#define NXP   340
#define NT    128
#define DXC   5.0f
#define DTC   0.001f
#define NSHOT 2
#define NREC  32
#define C1C   (9.0f / 8.0f)
#define C2C   (-1.0f / 24.0f)
#define RDX   (1.0f / 5.0f)

#define PITCH   344
#define FSTRIDE (NYP * PITCH)   // 116960 floats per field

// persistent-path per-shot field slots (22 per shot):
#define S_VY    0   // x2
#define S_VX    2   // x2
#define S_SYY   4   // x2
#define S_SXX   6   // x2
#define S_SXY   8   // x2
#define S_MSYYY 10  // x2
#define S_MSXYX 12  // x2
#define S_MSXYY 14  // x2
#define S_MSXXX 16  // x2
#define S_MVYY  18
#define S_MVYX  19
#define S_MVXY  20
#define S_MVXX  21
#define NFLD    22

__device__ __forceinline__ float ldf(const float* f, int y, int x) {
    return (y >= 0 && y < NYP && x >= 0 && x < NXP) ? f[y * PITCH + x] : 0.0f;
}
__device__ __forceinline__ float dpy(const float* f, int y, int x) {
    return (C1C * (ldf(f, y + 1, x) - ldf(f, y, x)) +
            C2C * (ldf(f, y + 2, x) - ldf(f, y - 1, x))) * RDX;
}
__device__ __forceinline__ float dmy(const float* f, int y, int x) {
    return (C1C * (ldf(f, y, x) - ldf(f, y - 1, x)) +
            C2C * (ldf(f, y + 1, x) - ldf(f, y - 2, x))) * RDX;
}
__device__ __forceinline__ float dpx(const float* f, int y, int x) {
    return (C1C * (ldf(f, y, x + 1) - ldf(f, y, x)) +
            C2C * (ldf(f, y, x + 2) - ldf(f, y, x - 1))) * RDX;
}
__device__ __forceinline__ float dmx(const float* f, int y, int x) {
    return (C1C * (ldf(f, y, x) - ldf(f, y, x - 1)) +
            C2C * (ldf(f, y, x + 1) - ldf(f, y, x - 2))) * RDX;
}

// params[0]=lam, [1]=lam+2mu, [2]=mu, [3]=buoyancy (edge-padded into PML)
__global__ void init_params_kernel(const float* __restrict__ lamb,
                                   const float* __restrict__ mu,
                                   const float* __restrict__ buo,
                                   float* __restrict__ params) {
    int x = blockIdx.x * blockDim.x + threadIdx.x;
    int y = blockIdx.y;
    if (x >= NXP || y >= NYP) return;
    int cy = y - PML; cy = cy < 0 ? 0 : (cy > NYI - 1 ? NYI - 1 : cy);
    int cx = x - PML; cx = cx < 0 ? 0 : (cx > NXI - 1 ? NXI - 1 : cx);
    float l = lamb[cy * NXI + cx];
    float m = mu[cy * NXI + cx];
    float b = buo[cy * NXI + cx];
    int idx = y * PITCH + x;
    params[0 * FSTRIDE + idx] = l;
    params[1 * FSTRIDE + idx] = l + 2.0f * m;
    params[2 * FSTRIDE + idx] = m;
    params[3 * FSTRIDE + idx] = b;
}

__global__ void init_decay_kernel(float* __restrict__ bdec) {
    int i = blockIdx.x * blockDim.x + threadIdx.x;
    if (i >= NYP + NXP) return;
    int idx = (i < NYP) ? i : i - NYP;
    float fx = (float)idx;
    float lo = fminf(fmaxf(((float)PML - fx) / (float)PML, 0.0f), 1.0f);
    float hi = fminf(fmaxf((fx - (float)(NYP - 1 - PML)) / (float)PML, 0.0f), 1.0f);
    float mx = fmaxf(lo, hi);
    float d0 = 3.0f * 2000.0f / (2.0f * (float)PML * DXC) * logf(1.0f / 1e-6f);
    bdec[i] = expf(-d0 * mx * mx * DTC);
}

// ------------------------- persistent cooperative path ----------------------

__device__ __forceinline__ void grid_barrier(unsigned* bar, unsigned nblk) {
    __syncthreads();
    if (threadIdx.x == 0) {
        __threadfence();  // release: make this block's writes agent-visible
        unsigned gen = __hip_atomic_load(&bar[1], __ATOMIC_RELAXED, __HIP_MEMORY_SCOPE_AGENT);
        unsigned arr = __hip_atomic_fetch_add(&bar[0], 1u, __ATOMIC_ACQ_REL, __HIP_MEMORY_SCOPE_AGENT);
        if (arr == nblk - 1u) {
            __hip_atomic_store(&bar[0], 0u, __ATOMIC_RELAXED, __HIP_MEMORY_SCOPE_AGENT);
            __hip_atomic_fetch_add(&bar[1], 1u, __ATOMIC_RELEASE, __HIP_MEMORY_SCOPE_AGENT);
        } else {
            while (__hip_atomic_load(&bar[1], __ATOMIC_RELAXED, __HIP_MEMORY_SCOPE_AGENT) == gen)
                __builtin_amdgcn_s_sleep(8);
        }
        __threadfence();  // acquire: observe all other blocks' writes
    }
    __syncthreads();
}

#define TILW 85   // 4 x-tiles of 85
#define NTY  32   // 32 y-tiles of 10..11 rows
// LDS region: (11+4) x (85+4) max
#define LDH 15
#define LDW 92

__global__ __launch_bounds__(256)
void persist_kernel(float* __restrict__ state, const float* __restrict__ params,
                    const float* __restrict__ bdec, const float* __restrict__ amps,
                    const int* __restrict__ sloc, const int* __restrict__ rloc,
                    float* __restrict__ out, unsigned* __restrict__ bar) {
    __shared__ float lvy[LDH][LDW];
    __shared__ float lvx[LDH][LDW];

    const int tidf = threadIdx.x;
    const int s    = blockIdx.x >> 7;          // 128 blocks per shot
    const int tile = blockIdx.x & 127;
    const int txi  = tile & 3;
    const int tyi  = tile >> 2;
    const int x0 = txi * TILW, x1 = x0 + TILW;
    const int y0 = (tyi * NYP) / NTY, y1 = ((tyi + 1) * NYP) / NTY;
    const int rx0 = max(x0 - 2, 0), rx1 = min(x1 + 2, NXP);
    const int ry0 = max(y0 - 2, 0), ry1 = min(y1 + 2, NYP);
    const int rw = rx1 - rx0, rh = ry1 - ry0;
    const int nreg = rw * rh;
    const int nint = (x1 - x0) * (y1 - y0);

    float* base = state + (size_t)s * NFLD * FSTRIDE;
    const int sy = sloc[s * 2 + 0] + PML;
    const int sx = sloc[s * 2 + 1] + PML;

    const float* lamp  = params + 0 * FSTRIDE;
    const float* lp2mp = params + 1 * FSTRIDE;
    const float* mup   = params + 2 * FSTRIDE;
    const float* buop  = params + 3 * FSTRIDE;

    for (int t = 0; t < NT; ++t) {
        const int c = t & 1, n = c ^ 1;
        const float* vyc    = base + (S_VY + c) * FSTRIDE;
        const float* vxc    = base + (S_VX + c) * FSTRIDE;
        float*       vyn    = base + (S_VY + n) * FSTRIDE;
        float*       vxn    = base + (S_VX + n) * FSTRIDE;
        const float* syyc   = base + (S_SYY + c) * FSTRIDE;
        const float* sxxc   = base + (S_SXX + c) * FSTRIDE;
        const float* sxyc   = base + (S_SXY + c) * FSTRIDE;
        float*       syyn   = base + (S_SYY + n) * FSTRIDE;
        float*       sxxn   = base + (S_SXX + n) * FSTRIDE;
        float*       sxyn   = base + (S_SXY + n) * FSTRIDE;
        const float* msyyyc = base + (S_MSYYY + c) * FSTRIDE;
        const float* msxyxc = base + (S_MSXYX + c) * FSTRIDE;
        const float* msxyyc = base + (S_MSXYY + c) * FSTRIDE;
        const float* msxxxc = base + (S_MSXXX + c) * FSTRIDE;
        float*       msyyyn = base + (S_MSYYY + n) * FSTRIDE;
        float*       msxyxn = base + (S_MSXYX + n) * FSTRIDE;
        float*       msxyyn = base + (S_MSXYY + n) * FSTRIDE;
        float*       msxxxn = base + (S_MSXXX + n) * FSTRIDE;
        float*       mvyy   = base + S_MVYY * FSTRIDE;
        float*       mvyx   = base + S_MVYX * FSTRIDE;
        float*       mvxy   = base + S_MVXY * FSTRIDE;
        float*       mvxx   = base + S_MVXX * FSTRIDE;
        const float amp_t = amps[s * NT + t];

        // ---- velocity phase over tile + 2-halo (redundant at halo) ----
        for (int i = tidf; i < nreg; i += 256) {
            int ly = i / rw, lx = i - ly * rw;
            int y = ry0 + ly, x = rx0 + lx;
            int idx = y * PITCH + x;
            float by = bdec[y], bx = bdec[NYP + x];
            float d1 = dpy(syyc, y, x);
            float m1 = by * msyyyc[idx] + (by - 1.0f) * d1;
            float d2 = dmx(sxyc, y, x);
            float m2 = bx * msxyxc[idx] + (bx - 1.0f) * d2;
            float nvy = vyc[idx] + DTC * buop[idx] * (d1 + m1 + d2 + m2);
            float d3 = dmy(sxyc, y, x);
            float m3 = by * msxyyc[idx] + (by - 1.0f) * d3;
            float d4 = dpx(sxxc, y, x);
            float m4 = bx * msxxxc[idx] + (bx - 1.0f) * d4;
            float nvx = vxc[idx] + DTC * buop[idx] * (d3 + m3 + d4 + m4);
            if (y == sy && x == sx) nvy += amp_t;
            lvy[ly][lx] = nvy;
            lvx[ly][lx] = nvx;
            if (y >= y0 && y < y1 && x >= x0 && x < x1) {
                vyn[idx] = nvy;  vxn[idx] = nvx;
                msyyyn[idx] = m1; msxyxn[idx] = m2;
                msxyyn[idx] = m3; msxxxn[idx] = m4;
            }
        }
        __syncthreads();

        // ---- stress phase over interior (velocities from LDS) ----
        for (int i = tidf; i < nint; i += 256) {
            int iy = i / TILW, ix = i - iy * TILW;
            int y = y0 + iy, x = x0 + ix;
            int ly = y - ry0, lx = x - rx0;
            int idx = y * PITCH + x;
            float by = bdec[y], bx = bdec[NYP + x];
            float vym2 = (y - 2 >= 0) ? lvy[ly - 2][lx] : 0.0f;
            float vym1 = (y - 1 >= 0) ? lvy[ly - 1][lx] : 0.0f;
            float vy0v = lvy[ly][lx];
            float vyp1 = (y + 1 < NYP) ? lvy[ly + 1][lx] : 0.0f;
            float vxm2 = (x - 2 >= 0) ? lvx[ly][lx - 2] : 0.0f;
            float vxm1 = (x - 1 >= 0) ? lvx[ly][lx - 1] : 0.0f;
            float vx0v = lvx[ly][lx];
            float vxp1 = (x + 1 < NXP) ? lvx[ly][lx + 1] : 0.0f;
            float d, m;
            d = (C1C * (vy0v - vym1) + C2C * (vyp1 - vym2)) * RDX;   // dmy(vy)
            m = by * mvyy[idx] + (by - 1.0f) * d; mvyy[idx] = m;
            float dvy_dy = d + m;
            d = (C1C * (vx0v - vxm1) + C2C * (vxp1 - vxm2)) * RDX;   // dmx(vx)
            m = bx * mvxx[idx] + (bx - 1.0f) * d; mvxx[idx] = m;
            float dvx_dx = d + m;
            syyn[idx] = syyc[idx] + DTC * (lp2mp[idx] * dvy_dy + lamp[idx] * dvx_dx);
            sxxn[idx] = sxxc[idx] + DTC * (lp2mp[idx] * dvx_dx + lamp[idx] * dvy_dy);
            float vyxm1 = (x - 1 >= 0) ? lvy[ly][lx - 1] : 0.0f;
            float vyxp1 = (x + 1 < NXP) ? lvy[ly][lx + 1] : 0.0f;
            float vyxp2 = (x + 2 < NXP) ? lvy[ly][lx + 2] : 0.0f;
            float vxym1 = (y - 1 >= 0) ? lvx[ly - 1][lx] : 0.0f;
            float vxyp1 = (y + 1 < NYP) ? lvx[ly + 1][lx] : 0.0f;
            float vxyp2 = (y + 2 < NYP) ? lvx[ly + 2][lx] : 0.0f;
            d = (C1C * (vyxp1 - vy0v) + C2C * (vyxp2 - vyxm1)) * RDX; // dpx(vy)
            m = bx * mvyx[idx] + (bx - 1.0f) * d; mvyx[idx] = m;
            float dvy_dx = d + m;
            d = (C1C * (vxyp1 - vx0v) + C2C * (vxyp2 - vxym1)) * RDX; // dpy(vx)
            m = by * mvxy[idx] + (by - 1.0f) * d; mvxy[idx] = m;
            float dvx_dy = d + m;
            sxyn[idx] = sxyc[idx] + DTC * mup[idx] * (dvy_dx + dvx_dy);
        }

        grid_barrier(bar, gridDim.x);

        // ---- receiver extraction for step t (post-barrier, buffer n) ----
        if (blockIdx.x == 0 && tidf < NSHOT * NREC) {
            int rs = tidf >> 5, rr = tidf & 31;
            int ry = rloc[(rs * NREC + rr) * 2 + 0] + PML;
            int rx = rloc[(rs * NREC + rr) * 2 + 1] + PML;
            const float* vyr = state + (size_t)rs * NFLD * FSTRIDE + (S_VY + n) * FSTRIDE;
            out[(rs * NREC + rr) * NT + t] = vyr[ry * PITCH + rx];
        }
    }
}

// ------------------------------ fallback path -------------------------------
// (round-1 proven multi-launch version, 13 fields/shot layout)

__global__ __launch_bounds__(256)
void vel_kernel(float* __restrict__ ws, const float* __restrict__ params,
                const float* __restrict__ bdec, const float* __restrict__ amps,
                const int* __restrict__ sloc, int t) {
    int x = blockIdx.x * 64 + threadIdx.x;
    int y = blockIdx.y * 4 + threadIdx.y;
    int s = blockIdx.z;
    if (x >= NXP) return;
    float* F = ws + (size_t)s * 13 * FSTRIDE;
    float* vy = F; float* vx = F + FSTRIDE;
    const float* syy = F + 2 * FSTRIDE;
    const float* sxx = F + 3 * FSTRIDE;
    const float* sxy = F + 4 * FSTRIDE;
    float* msyy_y = F + 9 * FSTRIDE;  float* msxy_x = F + 10 * FSTRIDE;
    float* msxy_y = F + 11 * FSTRIDE; float* msxx_x = F + 12 * FSTRIDE;
    float by = bdec[y], bx = bdec[NYP + x];
    int idx = y * PITCH + x;
    float buoy = params[3 * FSTRIDE + idx];
    float d, m;
    d = dpy(syy, y, x); m = by * msyy_y[idx] + (by - 1.0f) * d; msyy_y[idx] = m;
    float a1 = d + m;
    d = dmx(sxy, y, x); m = bx * msxy_x[idx] + (bx - 1.0f) * d; msxy_x[idx] = m;
    float nvy = vy[idx] + DTC * buoy * (a1 + d + m);
    d = dmy(sxy, y, x); m = by * msxy_y[idx] + (by - 1.0f) * d; msxy_y[idx] = m;
    float a2 = d + m;
    d = dpx(sxx, y, x); m = bx * msxx_x[idx] + (bx - 1.0f) * d; msxx_x[idx] = m;
    float nvx = vx[idx] + DTC * buoy * (a2 + d + m);
    int sy = sloc[s * 2 + 0] + PML, sx = sloc[s * 2 + 1] + PML;
    if (y == sy && x == sx) nvy += amps[s * NT + t];
    vy[idx] = nvy; vx[idx] = nvx;
}

__global__ __launch_bounds__(256)
void str_kernel(float* __restrict__ ws, const float* __restrict__ params,
                const float* __restrict__ bdec, const int* __restrict__ rloc,
                float* __restrict__ out, int t) {
    int x = blockIdx.x * 64 + threadIdx.x;
    int y = blockIdx.y * 4 + threadIdx.y;
    int s = blockIdx.z;
    float* F = ws + (size_t)s * 13 * FSTRIDE;
    const float* vy = F; const float* vx = F + FSTRIDE;
    float* syy = F + 2 * FSTRIDE; float* sxx = F + 3 * FSTRIDE; float* sxy = F + 4 * FSTRIDE;
    float* mvyy = F + 5 * FSTRIDE; float* mvyx = F + 6 * FSTRIDE;
    float* mvxy = F + 7 * FSTRIDE; float* mvxx = F + 8 * FSTRIDE;
    if (blockIdx.x == 0 && blockIdx.y == 0) {
        int tid = threadIdx.y * 64 + threadIdx.x;
        if (tid < NREC) {
            int ry = rloc[(s * NREC + tid) * 2 + 0] + PML;
            int rx = rloc[(s * NREC + tid) * 2 + 1] + PML;
            out[(s * NREC + tid) * NT + t] = vy[ry * PITCH + rx];
        }
    }
    if (x >= NXP) return;
    float by = bdec[y], bx = bdec[NYP + x];
    int idx = y * PITCH + x;
    float lam = params[idx], lp2m = params[FSTRIDE + idx], muv = params[2 * FSTRIDE + idx];
    float d, m;
    d = dmy(vy, y, x); m = by * mvyy[idx] + (by - 1.0f) * d; mvyy[idx] = m;
    float dvy_dy = d + m;
    d = dmx(vx, y, x); m = bx * mvxx[idx] + (bx - 1.0f) * d; mvxx[idx] = m;
    float dvx_dx = d + m;
    syy[idx] += DTC * (lp2m * dvy_dy + lam * dvx_dx);
    sxx[idx] += DTC * (lp2m * dvx_dx + lam * dvy_dy);
    d = dpx(vy, y, x); m = bx * mvyx[idx] + (bx - 1.0f) * d; mvyx[idx] = m;
    float dvy_dx = d + m;
    d = dpy(vx, y, x); m = by * mvxy[idx] + (by - 1.0f) * d; mvxy[idx] = m;
    float dvx_dy = d + m;
    sxy[idx] += DTC * muv * (dvy_dx + dvx_dy);
}

// ----------------------------------------------------------------------------

extern "C" void kernel_launch(void* const* d_in, const int* in_sizes, int n_in,
                              void* d_out, int out_size, void* d_ws, size_t ws_size,
                              hipStream_t stream) {
    const float* lamb = (const float*)d_in[0];
    const float* mu   = (const float*)d_in[1];
    const float* buo  = (const float*)d_in[2];
    const float* amps = (const float*)d_in[3];
    const int*   sloc = (const int*)d_in[4];
    const int*   rloc = (const int*)d_in[5];
    float* out = (float*)d_out;

    float* wsf = (float*)d_ws;
    // persistent layout: [bar 64f][state 44f*FSTRIDE][params 4f*FSTRIDE][bdec 680f]
    unsigned* bar = (unsigned*)wsf;
    float* state  = wsf + 64;
    float* params = wsf + 64 + (size_t)(2 * NFLD) * FSTRIDE;
    float* bdec   = wsf + 64 + (size_t)(2 * NFLD + 4) * FSTRIDE;
    size_t needed = (size_t)(64 + (2 * NFLD + 4) * FSTRIDE + NYP + NXP) * sizeof(float);

    dim3 pib(256, 1, 1), pig((NXP + 255) / 256, NYP, 1);

    if (ws_size >= needed) {
        (void)hipMemsetAsync(wsf, 0, (size_t)(64 + 2 * NFLD * FSTRIDE) * sizeof(float), stream);
        init_params_kernel<<<pig, pib, 0, stream>>>(lamb, mu, buo, params);
        init_decay_kernel<<<(NYP + NXP + 255) / 256, 256, 0, stream>>>(bdec);
        void* args[] = {&state, &params, &bdec, &amps, &sloc, &rloc, &out, &bar};
        (void)hipLaunchCooperativeKernel((void*)persist_kernel, dim3(2 * 128), dim3(256),
                                         args, 0, stream);
    } else {
        // round-1 fallback: state 26 fields at wsf+64, params/bdec after
        float* statef = wsf + 64;
        float* paramf = wsf + 64 + (size_t)26 * FSTRIDE;
        float* bdecf  = wsf + 64 + (size_t)30 * FSTRIDE;
        (void)hipMemsetAsync(statef, 0, (size_t)26 * FSTRIDE * sizeof(float), stream);
        init_params_kernel<<<pig, pib, 0, stream>>>(lamb, mu, buo, paramf);
        init_decay_kernel<<<(NYP + NXP + 255) / 256, 256, 0, stream>>>(bdecf);
        dim3 blk(64, 4, 1), grd((NXP + 63) / 64, NYP / 4, NSHOT);
        for (int t = 0; t < NT; ++t) {
            vel_kernel<<<grd, blk, 0, stream>>>(statef, paramf, bdecf, amps, sloc, t);
            str_kernel<<<grd, blk, 0, stream>>>(statef, paramf, bdecf, rloc, out, t);
        }
    }
}

// Round 4
// 3200.425 us; speedup vs baseline: 1.9328x; 1.9328x over previous
//
#include <hip/hip_runtime.h>

// ---------------------------------------------------------------------------
// Elastic 2D velocity-stress staggered FD + C-PML, 2 shots, 128 steps.
// Round 4: fused ONE kernel per time step (128 launches). Velocity computed
// redundantly on a +2 halo into LDS so the stress phase is block-local; the
// kernel boundary provides the inter-step global sync (L2 writeback lands in
// the warm 256MB LLC — unlike R3's in-kernel agent fence which invalidated L2
// every step and forced 23MB/step through HBM at 495 GB/s).
// PML-strip optimization: C-PML memory fields are exactly 0 outside their
// strips (b==1 -> m'=m), so interior cells skip those loads/stores entirely.
// Receivers for step t extracted at start of launch t+1 (+1 tail kernel).
// ---------------------------------------------------------------------------

#define NYI   300
#define NXI   300
#define PML   20
#define NYP   340
#define NXP   340
#define NT    128
#define DXC   5.0f
#define DTC   0.001f
#define NSHOT 2
#define NREC  32
#define C1C   (9.0f / 8.0f)
#define C2C   (-1.0f / 24.0f)
#define RDX   (1.0f / 5.0f)

#define PITCH   344
#define FSTRIDE (NYP * PITCH)   // 116960 floats per field

// per-shot field slots (22 per shot), double-buffered except stress-phase mem:
#define S_VY    0   // x2
#define S_VX    2   // x2
#define S_SYY   4   // x2
#define S_SXX   6   // x2
#define S_SXY   8   // x2
#define S_MSYYY 10  // x2
#define S_MSXYX 12  // x2
#define S_MSXYY 14  // x2
#define S_MSXXX 16  // x2
#define S_MVYY  18
#define S_MVYX  19
#define S_MVXY  20
#define S_MVXX  21
#define NFLD    22

__device__ __forceinline__ float ldf(const float* f, int y, int x) {
    return (y >= 0 && y < NYP && x >= 0 && x < NXP) ? f[y * PITCH + x] : 0.0f;
}
__device__ __forceinline__ float dpy(const float* f, int y, int x) {
    return (C1C * (ldf(f, y + 1, x) - ldf(f, y, x)) +
            C2C * (ldf(f, y + 2, x) - ldf(f, y - 1, x))) * RDX;
}
__device__ __forceinline__ float dmy(const float* f, int y, int x) {
    return (C1C * (ldf(f, y, x) - ldf(f, y - 1, x)) +
            C2C * (ldf(f, y + 1, x) - ldf(f, y - 2, x))) * RDX;
}
__device__ __forceinline__ float dpx(const float* f, int y, int x) {
    return (C1C * (ldf(f, y, x + 1) - ldf(f, y, x)) +
            C2C * (ldf(f, y, x + 2) - ldf(f, y, x - 1))) * RDX;
}
__device__ __forceinline__ float dmx(const float* f, int y, int x) {
    return (C1C * (ldf(f, y, x) - ldf(f, y, x - 1)) +
            C2C * (ldf(f, y, x + 1) - ldf(f, y, x - 2))) * RDX;
}

// params[0]=lam, [1]=lam+2mu, [2]=mu, [3]=buoyancy (edge-padded into PML)
__global__ void init_params_kernel(const float* __restrict__ lamb,
                                   const float* __restrict__ mu,
                                   const float* __restrict__ buo,
                                   float* __restrict__ params) {
    int x = blockIdx.x * blockDim.x + threadIdx.x;
    int y = blockIdx.y;
    if (x >= NXP || y >= NYP) return;
    int cy = y - PML; cy = cy < 0 ? 0 : (cy > NYI - 1 ? NYI - 1 : cy);
    int cx = x - PML; cx = cx < 0 ? 0 : (cx > NXI - 1 ? NXI - 1 : cx);
    float l = lamb[cy * NXI + cx];
    float m = mu[cy * NXI + cx];
    float b = buo[cy * NXI + cx];
    int idx = y * PITCH + x;
    params[0 * FSTRIDE + idx] = l;
    params[1 * FSTRIDE + idx] = l + 2.0f * m;
    params[2 * FSTRIDE + idx] = m;
    params[3 * FSTRIDE + idx] = b;
}

__global__ void init_decay_kernel(float* __restrict__ bdec) {
    int i = blockIdx.x * blockDim.x + threadIdx.x;
    if (i >= NYP + NXP) return;
    int idx = (i < NYP) ? i : i - NYP;
    float fx = (float)idx;
    float lo = fminf(fmaxf(((float)PML - fx) / (float)PML, 0.0f), 1.0f);
    float hi = fminf(fmaxf((fx - (float)(NYP - 1 - PML)) / (float)PML, 0.0f), 1.0f);
    float mx = fmaxf(lo, hi);
    float d0 = 3.0f * 2000.0f / (2.0f * (float)PML * DXC) * logf(1.0f / 1e-6f);
    bdec[i] = expf(-d0 * mx * mx * DTC);
    // note: exactly 1.0f outside the strips (exp(-0)); strip predicate is b<1
}

#define TILW 85   // 4 x-tiles of 85
#define NTY  32   // 32 y-tiles of 10..11 rows
#define LDH 15    // (11+4) max region height
#define LDW 92    // (85+4) + pad

__global__ __launch_bounds__(256)
void step_kernel(float* __restrict__ state, const float* __restrict__ params,
                 const float* __restrict__ bdec, const float* __restrict__ amps,
                 const int* __restrict__ sloc, const int* __restrict__ rloc,
                 float* __restrict__ out, int t) {
    __shared__ float lvy[LDH][LDW];
    __shared__ float lvx[LDH][LDW];

    const int tidf = threadIdx.x;
    const int s    = blockIdx.z;
    const int txi  = blockIdx.x;
    const int tyi  = blockIdx.y;
    const int x0 = txi * TILW, x1 = x0 + TILW;
    const int y0 = (tyi * NYP) / NTY, y1 = ((tyi + 1) * NYP) / NTY;
    const int rx0 = max(x0 - 2, 0), rx1 = min(x1 + 2, NXP);
    const int ry0 = max(y0 - 2, 0), ry1 = min(y1 + 2, NYP);
    const int rw = rx1 - rx0, rh = ry1 - ry0;
    const int nreg = rw * rh;
    const int nint = (x1 - x0) * (y1 - y0);

    const int c = t & 1, n = c ^ 1;
    float* base = state + (size_t)s * NFLD * FSTRIDE;
    const float* vyc    = base + (S_VY + c) * FSTRIDE;
    const float* vxc    = base + (S_VX + c) * FSTRIDE;
    float*       vyn    = base + (S_VY + n) * FSTRIDE;
    float*       vxn    = base + (S_VX + n) * FSTRIDE;
    const float* syyc   = base + (S_SYY + c) * FSTRIDE;
    const float* sxxc   = base + (S_SXX + c) * FSTRIDE;
    const float* sxyc   = base + (S_SXY + c) * FSTRIDE;
    float*       syyn   = base + (S_SYY + n) * FSTRIDE;
    float*       sxxn   = base + (S_SXX + n) * FSTRIDE;
    float*       sxyn   = base + (S_SXY + n) * FSTRIDE;
    const float* msyyyc = base + (S_MSYYY + c) * FSTRIDE;
    const float* msxyxc = base + (S_MSXYX + c) * FSTRIDE;
    const float* msxyyc = base + (S_MSXYY + c) * FSTRIDE;
    const float* msxxxc = base + (S_MSXXX + c) * FSTRIDE;
    float*       msyyyn = base + (S_MSYYY + n) * FSTRIDE;
    float*       msxyxn = base + (S_MSXYX + n) * FSTRIDE;
    float*       msxyyn = base + (S_MSXYY + n) * FSTRIDE;
    float*       msxxxn = base + (S_MSXXX + n) * FSTRIDE;
    float*       mvyy   = base + S_MVYY * FSTRIDE;
    float*       mvyx   = base + S_MVYX * FSTRIDE;
    float*       mvxy   = base + S_MVXY * FSTRIDE;
    float*       mvxx   = base + S_MVXX * FSTRIDE;

    const int sy = sloc[s * 2 + 0] + PML;
    const int sx = sloc[s * 2 + 1] + PML;
    const float amp_t = amps[s * NT + t];

    // ---- receiver extraction for step t-1 (buffer c, fully written last
    //      launch; this launch only writes buffer n) ----
    if (t > 0 && blockIdx.x == 0 && blockIdx.y == 0 && s == 0 && tidf < NSHOT * NREC) {
        int rs = tidf >> 5, rr = tidf & 31;
        int ry = rloc[(rs * NREC + rr) * 2 + 0] + PML;
        int rx = rloc[(rs * NREC + rr) * 2 + 1] + PML;
        const float* vyr = state + (size_t)rs * NFLD * FSTRIDE + (S_VY + c) * FSTRIDE;
        out[(rs * NREC + rr) * NT + (t - 1)] = vyr[ry * PITCH + rx];
    }

    const float* lamp  = params + 0 * FSTRIDE;
    const float* lp2mp = params + 1 * FSTRIDE;
    const float* mup   = params + 2 * FSTRIDE;
    const float* buop  = params + 3 * FSTRIDE;

    // ---- velocity phase over tile + 2-halo (redundant at halo) ----
    for (int i = tidf; i < nreg; i += 256) {
        int ly = i / rw, lx = i - ly * rw;
        int y = ry0 + ly, x = rx0 + lx;
        int idx = y * PITCH + x;
        float by = bdec[y], bx = bdec[NYP + x];
        bool ys = (by < 1.0f), xs = (bx < 1.0f);
        float d1 = dpy(syyc, y, x);
        float m1 = ys ? (by * msyyyc[idx] + (by - 1.0f) * d1) : 0.0f;
        float d2 = dmx(sxyc, y, x);
        float m2 = xs ? (bx * msxyxc[idx] + (bx - 1.0f) * d2) : 0.0f;
        float nvy = vyc[idx] + DTC * buop[idx] * (d1 + m1 + d2 + m2);
        float d3 = dmy(sxyc, y, x);
        float m3 = ys ? (by * msxyyc[idx] + (by - 1.0f) * d3) : 0.0f;
        float d4 = dpx(sxxc, y, x);
        float m4 = xs ? (bx * msxxxc[idx] + (bx - 1.0f) * d4) : 0.0f;
        float nvx = vxc[idx] + DTC * buop[idx] * (d3 + m3 + d4 + m4);
        if (y == sy && x == sx) nvy += amp_t;
        lvy[ly][lx] = nvy;
        lvx[ly][lx] = nvx;
        if (y >= y0 && y < y1 && x >= x0 && x < x1) {
            vyn[idx] = nvy;  vxn[idx] = nvx;
            if (ys) { msyyyn[idx] = m1; msxyyn[idx] = m3; }
            if (xs) { msxyxn[idx] = m2; msxxxn[idx] = m4; }
        }
    }
    __syncthreads();

    // ---- stress phase over interior (velocities from LDS) ----
    for (int i = tidf; i < nint; i += 256) {
        int iy = i / TILW, ix = i - iy * TILW;
        int y = y0 + iy, x = x0 + ix;
        int ly = y - ry0, lx = x - rx0;
        int idx = y * PITCH + x;
        float by = bdec[y], bx = bdec[NYP + x];
        bool ys = (by < 1.0f), xs = (bx < 1.0f);
        float vym2 = (y - 2 >= 0) ? lvy[ly - 2][lx] : 0.0f;
        float vym1 = (y - 1 >= 0) ? lvy[ly - 1][lx] : 0.0f;
        float vy0v = lvy[ly][lx];
        float vyp1 = (y + 1 < NYP) ? lvy[ly + 1][lx] : 0.0f;
        float vxm2 = (x - 2 >= 0) ? lvx[ly][lx - 2] : 0.0f;
        float vxm1 = (x - 1 >= 0) ? lvx[ly][lx - 1] : 0.0f;
        float vx0v = lvx[ly][lx];
        float vxp1 = (x + 1 < NXP) ? lvx[ly][lx + 1] : 0.0f;
        float d, m;
        d = (C1C * (vy0v - vym1) + C2C * (vyp1 - vym2)) * RDX;   // dmy(vy)
        m = ys ? (by * mvyy[idx] + (by - 1.0f) * d) : 0.0f;
        if (ys) mvyy[idx] = m;
        float dvy_dy = d + m;
        d = (C1C * (vx0v - vxm1) + C2C * (vxp1 - vxm2)) * RDX;   // dmx(vx)
        m = xs ? (bx * mvxx[idx] + (bx - 1.0f) * d) : 0.0f;
        if (xs) mvxx[idx] = m;
        float dvx_dx = d + m;
        syyn[idx] = syyc[idx] + DTC * (lp2mp[idx] * dvy_dy + lamp[idx] * dvx_dx);
        sxxn[idx] = sxxc[idx] + DTC * (lp2mp[idx] * dvx_dx + lamp[idx] * dvy_dy);
        float vyxm1 = (x - 1 >= 0) ? lvy[ly][lx - 1] : 0.0f;
        float vyxp1 = (x + 1 < NXP) ? lvy[ly][lx + 1] : 0.0f;
        float vyxp2 = (x + 2 < NXP) ? lvy[ly][lx + 2] : 0.0f;
        float vxym1 = (y - 1 >= 0) ? lvx[ly - 1][lx] : 0.0f;
        float vxyp1 = (y + 1 < NYP) ? lvx[ly + 1][lx] : 0.0f;
        float vxyp2 = (y + 2 < NYP) ? lvx[ly + 2][lx] : 0.0f;
        d = (C1C * (vyxp1 - vy0v) + C2C * (vyxp2 - vyxm1)) * RDX; // dpx(vy)
        m = xs ? (bx * mvyx[idx] + (bx - 1.0f) * d) : 0.0f;
        if (xs) mvyx[idx] = m;
        float dvy_dx = d + m;
        d = (C1C * (vxyp1 - vx0v) + C2C * (vxyp2 - vxym1)) * RDX; // dpy(vx)
        m = ys ? (by * mvxy[idx] + (by - 1.0f) * d) : 0.0f;
        if (ys) mvxy[idx] = m;
        float dvx_dy = d + m;
        sxyn[idx] = sxyc[idx] + DTC * mup[idx] * (dvy_dx + dvx_dy);
    }
}

// receivers for the final step (buffer written by launch t=NT-1)
__global__ void tail_recv_kernel(const float* __restrict__ state,
                                 const int* __restrict__ rloc,
                                 float* __restrict__ out) {
    int tid = threadIdx.x;
    if (tid >= NSHOT * NREC) return;
    int rs = tid >> 5, rr = tid & 31;
    int ry = rloc[(rs * NREC + rr) * 2 + 0] + PML;
    int rx = rloc[(rs * NREC + rr) * 2 + 1] + PML;
    const int n = ((NT - 1) & 1) ^ 1;
    const float* vyr = state + (size_t)rs * NFLD * FSTRIDE + (S_VY + n) * FSTRIDE;
    out[(rs * NREC + rr) * NT + (NT - 1)] = vyr[ry * PITCH + rx];
}

// ------------------------------ fallback path -------------------------------

__global__ __launch_bounds__(256)
void vel_kernel(float* __restrict__ ws, const float* __restrict__ params,
                const float* __restrict__ bdec, const float* __restrict__ amps,
                const int* __restrict__ sloc, int t) {
    int x = blockIdx.x * 64 + threadIdx.x;
    int y = blockIdx.y * 4 + threadIdx.y;
    int s = blockIdx.z;
    if (x >= NXP) return;
    float* F = ws + (size_t)s * 13 * FSTRIDE;
    float* vy = F; float* vx = F + FSTRIDE;
    const float* syy = F + 2 * FSTRIDE;
    const float* sxx = F + 3 * FSTRIDE;
    const float* sxy = F + 4 * FSTRIDE;
    float* msyy_y = F + 9 * FSTRIDE;  float* msxy_x = F + 10 * FSTRIDE;
    float* msxy_y = F + 11 * FSTRIDE; float* msxx_x = F + 12 * FSTRIDE;
    float by = bdec[y], bx = bdec[NYP + x];
    int idx = y * PITCH + x;
    float buoy = params[3 * FSTRIDE + idx];
    float d, m;
    d = dpy(syy, y, x); m = by * msyy_y[idx] + (by - 1.0f) * d; msyy_y[idx] = m;
    float a1 = d + m;
    d = dmx(sxy, y, x); m = bx * msxy_x[idx] + (bx - 1.0f) * d; msxy_x[idx] = m;
    float nvy = vy[idx] + DTC * buoy * (a1 + d + m);
    d = dmy(sxy, y, x); m = by * msxy_y[idx] + (by - 1.0f) * d; msxy_y[idx] = m;
    float a2 = d + m;
    d = dpx(sxx, y, x); m = bx * msxx_x[idx] + (bx - 1.0f) * d; msxx_x[idx] = m;
    float nvx = vx[idx] + DTC * buoy * (a2 + d + m);
    int sy = sloc[s * 2 + 0] + PML, sx = sloc[s * 2 + 1] + PML;
    if (y == sy && x == sx) nvy += amps[s * NT + t];
    vy[idx] = nvy; vx[idx] = nvx;
}

__global__ __launch_bounds__(256)
void str_kernel(float* __restrict__ ws, const float* __restrict__ params,
                const float* __restrict__ bdec, const int* __restrict__ rloc,
                float* __restrict__ out, int t) {
    int x = blockIdx.x * 64 + threadIdx.x;
    int y = blockIdx.y * 4 + threadIdx.y;
    int s = blockIdx.z;
    float* F = ws + (size_t)s * 13 * FSTRIDE;
    const float* vy = F; const float* vx = F + FSTRIDE;
    float* syy = F + 2 * FSTRIDE; float* sxx = F + 3 * FSTRIDE; float* sxy = F + 4 * FSTRIDE;
    float* mvyy = F + 5 * FSTRIDE; float* mvyx = F + 6 * FSTRIDE;
    float* mvxy = F + 7 * FSTRIDE; float* mvxx = F + 8 * FSTRIDE;
    if (blockIdx.x == 0 && blockIdx.y == 0) {
        int tid = threadIdx.y * 64 + threadIdx.x;
        if (tid < NREC) {
            int ry = rloc[(s * NREC + tid) * 2 + 0] + PML;
            int rx = rloc[(s * NREC + tid) * 2 + 1] + PML;
            out[(s * NREC + tid) * NT + t] = vy[ry * PITCH + rx];
        }
    }
    if (x >= NXP) return;
    float by = bdec[y], bx = bdec[NYP + x];
    int idx = y * PITCH + x;
    float lam = params[idx], lp2m = params[FSTRIDE + idx], muv = params[2 * FSTRIDE + idx];
    float d, m;
    d = dmy(vy, y, x); m = by * mvyy[idx] + (by - 1.0f) * d; mvyy[idx] = m;
    float dvy_dy = d + m;
    d = dmx(vx, y, x); m = bx * mvxx[idx] + (bx - 1.0f) * d; mvxx[idx] = m;
    float dvx_dx = d + m;
    syy[idx] += DTC * (lp2m * dvy_dy + lam * dvx_dx);
    sxx[idx] += DTC * (lp2m * dvx_dx + lam * dvy_dy);
    d = dpx(vy, y, x); m = bx * mvyx[idx] + (bx - 1.0f) * d; mvyx[idx] = m;
    float dvy_dx = d + m;
    d = dpy(vx, y, x); m = by * mvxy[idx] + (by - 1.0f) * d; mvxy[idx] = m;
    float dvx_dy = d + m;
    sxy[idx] += DTC * muv * (dvy_dx + dvx_dy);
}

// ----------------------------------------------------------------------------

extern "C" void kernel_launch(void* const* d_in, const int* in_sizes, int n_in,
                              void* d_out, int out_size, void* d_ws, size_t ws_size,
                              hipStream_t stream) {
    const float* lamb = (const float*)d_in[0];
    const float* mu   = (const float*)d_in[1];
    const float* buo  = (const float*)d_in[2];
    const float* amps = (const float*)d_in[3];
    const int*   sloc = (const int*)d_in[4];
    const int*   rloc = (const int*)d_in[5];
    float* out = (float*)d_out;

    float* wsf = (float*)d_ws;
    // layout: [64f pad][state 44f*FSTRIDE][params 4f*FSTRIDE][bdec 680f]
    float* state  = wsf + 64;
    float* params = wsf + 64 + (size_t)(2 * NFLD) * FSTRIDE;
    float* bdec   = wsf + 64 + (size_t)(2 * NFLD + 4) * FSTRIDE;
    size_t needed = (size_t)(64 + (2 * NFLD + 4) * FSTRIDE + NYP + NXP) * sizeof(float);

    dim3 pib(256, 1, 1), pig((NXP + 255) / 256, NYP, 1);

    if (ws_size >= needed) {
        (void)hipMemsetAsync(state, 0, (size_t)(2 * NFLD) * FSTRIDE * sizeof(float), stream);
        init_params_kernel<<<pig, pib, 0, stream>>>(lamb, mu, buo, params);
        init_decay_kernel<<<(NYP + NXP + 255) / 256, 256, 0, stream>>>(bdec);
        dim3 grd(4, NTY, NSHOT);
        for (int t = 0; t < NT; ++t) {
            step_kernel<<<grd, dim3(256), 0, stream>>>(state, params, bdec, amps,
                                                       sloc, rloc, out, t);
        }
        tail_recv_kernel<<<1, 64, 0, stream>>>(state, rloc, out);
    } else {
        float* statef = wsf + 64;
        float* paramf = wsf + 64 + (size_t)26 * FSTRIDE;
        float* bdecf  = wsf + 64 + (size_t)30 * FSTRIDE;
        (void)hipMemsetAsync(statef, 0, (size_t)26 * FSTRIDE * sizeof(float), stream);
        init_params_kernel<<<pig, pib, 0, stream>>>(lamb, mu, buo, paramf);
        init_decay_kernel<<<(NYP + NXP + 255) / 256, 256, 0, stream>>>(bdecf);
        dim3 blk(64, 4, 1), grd((NXP + 63) / 64, NYP / 4, NSHOT);
        for (int t = 0; t < NT; ++t) {
            vel_kernel<<<grd, blk, 0, stream>>>(statef, paramf, bdecf, amps, sloc, t);
            str_kernel<<<grd, blk, 0, stream>>>(statef, paramf, bdecf, rloc, out, t);
        }
    }
}

// Round 5
// 2007.861 us; speedup vs baseline: 3.0808x; 1.5939x over previous
//
#include <hip/hip_runtime.h>

// ---------------------------------------------------------------------------
// Elastic 2D velocity-stress staggered FD + C-PML, 2 shots, 128 steps.
// Round 5: persistent cooperative kernel, LDS-RESIDENT state, neighbor-only
// sync. 256 blocks = 2 shots x (8x16) tiles; all 13 fields live in LDS for
// the whole run. Per phase, only 2-wide boundary strips go to global via
// relaxed agent-scope (sc1/LLC) atomic stores; neighbors spin on per-block
// flags (relaxed agent loads). NO agent fences -> no L2 invalidation (R3's
// mistake). __syncthreads' implicit vmcnt(0) drain orders strips before flag.
// Flag protocol: phase V of step t waits nbr flagS >= t (stress strips of
// step t-1 consumed+published); phase S waits nbr flagV >= t+1. Symmetric, so
// a writer can't overwrite strips a neighbor hasn't read.
// ---------------------------------------------------------------------------

#define NYI   300
#define NXI   300
#define PML   20
#define NYP   340
#define NXP   340
#define NT    128
#define DXC   5.0f
#define DTC   0.001f
#define NSHOT 2
#define NREC  32
#define C1C   (9.0f / 8.0f)
#define C2C   (-1.0f / 24.0f)
#define RDX   (1.0f / 5.0f)

#define PITCH   344
#define FSTRIDE (NYP * PITCH)

// tile grid per shot
#define TX 8
#define TY 16
#define TW 43              // ceil(340/8)
#define TH 22              // ceil(340/16)
#define RINGH 26           // TH + 4
#define RINGW 48           // TW + 4 (+1 pad)

__device__ __forceinline__ float aload(const float* p) {
    return __hip_atomic_load(p, __ATOMIC_RELAXED, __HIP_MEMORY_SCOPE_AGENT);
}
__device__ __forceinline__ void astore(float* p, float v) {
    __hip_atomic_store(p, v, __ATOMIC_RELAXED, __HIP_MEMORY_SCOPE_AGENT);
}

// params[0]=lam, [1]=lam+2mu, [2]=mu, [3]=buoyancy (edge-padded into PML)
__global__ void init_params_kernel(const float* __restrict__ lamb,
                                   const float* __restrict__ mu,
                                   const float* __restrict__ buo,
                                   float* __restrict__ params) {
    int x = blockIdx.x * blockDim.x + threadIdx.x;
    int y = blockIdx.y;
    if (x >= NXP || y >= NYP) return;
    int cy = y - PML; cy = cy < 0 ? 0 : (cy > NYI - 1 ? NYI - 1 : cy);
    int cx = x - PML; cx = cx < 0 ? 0 : (cx > NXI - 1 ? NXI - 1 : cx);
    float l = lamb[cy * NXI + cx];
    float m = mu[cy * NXI + cx];
    float b = buo[cy * NXI + cx];
    int idx = y * PITCH + x;
    params[0 * FSTRIDE + idx] = l;
    params[1 * FSTRIDE + idx] = l + 2.0f * m;
    params[2 * FSTRIDE + idx] = m;
    params[3 * FSTRIDE + idx] = b;
}

__global__ void init_decay_kernel(float* __restrict__ bdec) {
    int i = blockIdx.x * blockDim.x + threadIdx.x;
    if (i >= NYP + NXP) return;
    int idx = (i < NYP) ? i : i - NYP;
    float fx = (float)idx;
    float lo = fminf(fmaxf(((float)PML - fx) / (float)PML, 0.0f), 1.0f);
    float hi = fminf(fmaxf((fx - (float)(NYP - 1 - PML)) / (float)PML, 0.0f), 1.0f);
    float mx = fmaxf(lo, hi);
    float d0 = 3.0f * 2000.0f / (2.0f * (float)PML * DXC) * logf(1.0f / 1e-6f);
    bdec[i] = expf(-d0 * mx * mx * DTC);
}

__global__ __launch_bounds__(256)
void persist2_kernel(float* __restrict__ strips, const float* __restrict__ params,
                     const float* __restrict__ bdec, const float* __restrict__ amps,
                     const int* __restrict__ sloc, const int* __restrict__ rloc,
                     float* __restrict__ out, unsigned* __restrict__ flags) {
    // halo-ring fields (own interior + 2-cell halo from neighbors)
    __shared__ float vyH[RINGH][RINGW], vxH[RINGH][RINGW];
    __shared__ float syyH[RINGH][RINGW], sxxH[RINGH][RINGW], sxyH[RINGH][RINGW];
    // interior-only C-PML memories: 0 msyyy 1 msxyx 2 msxyy 3 msxxx
    //                               4 mvyy  5 mvxx  6 mvyx  7 mvxy
    __shared__ float mA[8][TH][44];
    __shared__ float byL[TH], bxL[TW];

    const int tid = threadIdx.x;
    const int s = blockIdx.x >> 7, tile = blockIdx.x & 127;
    const int txi = tile & 7, tyi = tile >> 3;
    const int x0 = txi * TW, x1 = min(x0 + TW, NXP);
    const int y0 = tyi * TH, y1 = min(y0 + TH, NYP);
    const int w = x1 - x0, h = y1 - y0, nint = w * h;

    unsigned* flagV = flags;
    unsigned* flagS = flags + 256;
    float* gb   = strips + (size_t)s * 5 * FSTRIDE;
    float* gvy  = gb + 0 * FSTRIDE;
    float* gvx  = gb + 1 * FSTRIDE;
    float* gsyy = gb + 2 * FSTRIDE;
    float* gsxx = gb + 3 * FSTRIDE;
    float* gsxy = gb + 4 * FSTRIDE;

    // neighbors: 0 up, 1 down, 2 left, 3 right (-1 if absent)
    int nbr0 = (tyi > 0)      ? (s << 7) + ((tyi - 1) << 3) + txi : -1;
    int nbr1 = (tyi < TY - 1) ? (s << 7) + ((tyi + 1) << 3) + txi : -1;
    int nbr2 = (txi > 0)      ? (s << 7) + (tyi << 3) + txi - 1   : -1;
    int nbr3 = (txi < TX - 1) ? (s << 7) + (tyi << 3) + txi + 1   : -1;
    int mynbr = -1;
    if (tid == 0) mynbr = nbr0;
    if (tid == 1) mynbr = nbr1;
    if (tid == 2) mynbr = nbr2;
    if (tid == 3) mynbr = nbr3;

    // zero LDS state (initial condition is all-zero)
    for (int i = tid; i < RINGH * RINGW; i += 256) {
        int r = i / RINGW, c = i - r * RINGW;
        vyH[r][c] = 0.0f; vxH[r][c] = 0.0f;
        syyH[r][c] = 0.0f; sxxH[r][c] = 0.0f; sxyH[r][c] = 0.0f;
    }
    for (int i = tid; i < 8 * TH * 44; i += 256) ((float*)mA)[i] = 0.0f;
    if (tid < h) byL[tid] = bdec[y0 + tid];
    if (tid < w) bxL[tid] = bdec[NYP + x0 + tid];

    const int sy = sloc[s * 2 + 0] + PML;
    const int sx = sloc[s * 2 + 1] + PML;

    bool hasRec = false; int recOff = 0, rly = 0, rlx = 0;
    if (tid < NSHOT * NREC) {
        int rs = tid >> 5, rr = tid & 31;
        if (rs == s) {
            int ry = rloc[(rs * NREC + rr) * 2 + 0] + PML;
            int rx = rloc[(rs * NREC + rr) * 2 + 1] + PML;
            if (ry >= y0 && ry < y1 && rx >= x0 && rx < x1) {
                hasRec = true; recOff = (rs * NREC + rr) * NT;
                rly = ry - y0 + 2; rlx = rx - x0 + 2;
            }
        }
    }
    __syncthreads();

    for (int t = 0; t < NT; ++t) {
        // ============ PHASE V: velocity update ============
        if (tid < 4 && mynbr >= 0) {
            while (__hip_atomic_load(&flagS[mynbr], __ATOMIC_RELAXED,
                                     __HIP_MEMORY_SCOPE_AGENT) < (unsigned)t)
                __builtin_amdgcn_s_sleep(1);
        }
        __syncthreads();
        // pull stress halos (2-wide strips from the 4 neighbors)
        if (nbr0 >= 0) for (int j = tid; j < 2 * w; j += 256) {
            int dy = j / w, lx = j - dy * w; int gi = (y0 - 2 + dy) * PITCH + x0 + lx;
            syyH[dy][2 + lx] = aload(&gsyy[gi]);
            sxxH[dy][2 + lx] = aload(&gsxx[gi]);
            sxyH[dy][2 + lx] = aload(&gsxy[gi]);
        }
        if (nbr1 >= 0) for (int j = tid; j < 2 * w; j += 256) {
            int dy = j / w, lx = j - dy * w; int gi = (y1 + dy) * PITCH + x0 + lx;
            syyH[h + 2 + dy][2 + lx] = aload(&gsyy[gi]);
            sxxH[h + 2 + dy][2 + lx] = aload(&gsxx[gi]);
            sxyH[h + 2 + dy][2 + lx] = aload(&gsxy[gi]);
        }
        if (nbr2 >= 0) for (int j = tid; j < 2 * h; j += 256) {
            int dx = j / h, ly = j - dx * h; int gi = (y0 + ly) * PITCH + x0 - 2 + dx;
            syyH[2 + ly][dx] = aload(&gsyy[gi]);
            sxxH[2 + ly][dx] = aload(&gsxx[gi]);
            sxyH[2 + ly][dx] = aload(&gsxy[gi]);
        }
        if (nbr3 >= 0) for (int j = tid; j < 2 * h; j += 256) {
            int dx = j / h, ly = j - dx * h; int gi = (y0 + ly) * PITCH + x1 + dx;
            syyH[2 + ly][w + 2 + dx] = aload(&gsyy[gi]);
            sxxH[2 + ly][w + 2 + dx] = aload(&gsxx[gi]);
            sxyH[2 + ly][w + 2 + dx] = aload(&gsxy[gi]);
        }
        __syncthreads();

        const float amp_t = amps[s * NT + t];
        for (int i = tid; i < nint; i += 256) {
            int ly = i / w, lx = i - ly * w;
            int y = y0 + ly, x = x0 + lx;
            int hy = ly + 2, hx = lx + 2;
            int gi = y * PITCH + x;
            float by = byL[ly], bx = bxL[lx];
            float d1 = (C1C * (syyH[hy + 1][hx] - syyH[hy][hx]) +
                        C2C * (syyH[hy + 2][hx] - syyH[hy - 1][hx])) * RDX;   // dpy(syy)
            float m1 = by * mA[0][ly][lx] + (by - 1.0f) * d1; mA[0][ly][lx] = m1;
            float d2 = (C1C * (sxyH[hy][hx] - sxyH[hy][hx - 1]) +
                        C2C * (sxyH[hy][hx + 1] - sxyH[hy][hx - 2])) * RDX;   // dmx(sxy)
            float m2 = bx * mA[1][ly][lx] + (bx - 1.0f) * d2; mA[1][ly][lx] = m2;
            float buo = params[3 * FSTRIDE + gi];
            float nvy = vyH[hy][hx] + DTC * buo * (d1 + m1 + d2 + m2);
            float d3 = (C1C * (sxyH[hy][hx] - sxyH[hy - 1][hx]) +
                        C2C * (sxyH[hy + 1][hx] - sxyH[hy - 2][hx])) * RDX;   // dmy(sxy)
            float m3 = by * mA[2][ly][lx] + (by - 1.0f) * d3; mA[2][ly][lx] = m3;
            float d4 = (C1C * (sxxH[hy][hx + 1] - sxxH[hy][hx]) +
                        C2C * (sxxH[hy][hx + 2] - sxxH[hy][hx - 1])) * RDX;   // dpx(sxx)
            float m4 = bx * mA[3][ly][lx] + (bx - 1.0f) * d4; mA[3][ly][lx] = m4;
            float nvx = vxH[hy][hx] + DTC * buo * (d3 + m3 + d4 + m4);
            if (y == sy && x == sx) nvy += amp_t;
            vyH[hy][hx] = nvy; vxH[hy][hx] = nvx;
            if (ly < 2 || ly >= h - 2 || lx < 2 || lx >= w - 2) {
                astore(&gvy[gi], nvy);
                astore(&gvx[gi], nvx);
            }
        }
        __builtin_amdgcn_s_waitcnt(0);
        __syncthreads();   // all waves' strip stores drained (vmcnt 0) here
        if (tid == 0)
            __hip_atomic_store(&flagV[blockIdx.x], (unsigned)(t + 1),
                               __ATOMIC_RELAXED, __HIP_MEMORY_SCOPE_AGENT);
        if (hasRec) out[recOff + t] = vyH[rly][rlx];

        // ============ PHASE S: stress update ============
        if (tid < 4 && mynbr >= 0) {
            while (__hip_atomic_load(&flagV[mynbr], __ATOMIC_RELAXED,
                                     __HIP_MEMORY_SCOPE_AGENT) < (unsigned)(t + 1))
                __builtin_amdgcn_s_sleep(1);
        }
        __syncthreads();
        // pull velocity halos
        if (nbr0 >= 0) for (int j = tid; j < 2 * w; j += 256) {
            int dy = j / w, lx = j - dy * w; int gi = (y0 - 2 + dy) * PITCH + x0 + lx;
            vyH[dy][2 + lx] = aload(&gvy[gi]);
            vxH[dy][2 + lx] = aload(&gvx[gi]);
        }
        if (nbr1 >= 0) for (int j = tid; j < 2 * w; j += 256) {
            int dy = j / w, lx = j - dy * w; int gi = (y1 + dy) * PITCH + x0 + lx;
            vyH[h + 2 + dy][2 + lx] = aload(&gvy[gi]);
            vxH[h + 2 + dy][2 + lx] = aload(&gvx[gi]);
        }
        if (nbr2 >= 0) for (int j = tid; j < 2 * h; j += 256) {
            int dx = j / h, ly = j - dx * h; int gi = (y0 + ly) * PITCH + x0 - 2 + dx;
            vyH[2 + ly][dx] = aload(&gvy[gi]);
            vxH[2 + ly][dx] = aload(&gvx[gi]);
        }
        if (nbr3 >= 0) for (int j = tid; j < 2 * h; j += 256) {
            int dx = j / h, ly = j - dx * h; int gi = (y0 + ly) * PITCH + x1 + dx;
            vyH[2 + ly][w + 2 + dx] = aload(&gvy[gi]);
            vxH[2 + ly][w + 2 + dx] = aload(&gvx[gi]);
        }
        __syncthreads();

        for (int i = tid; i < nint; i += 256) {
            int ly = i / w, lx = i - ly * w;
            int y = y0 + ly, x = x0 + lx;
            int hy = ly + 2, hx = lx + 2;
            int gi = y * PITCH + x;
            float by = byL[ly], bx = bxL[lx];
            float d, m;
            d = (C1C * (vyH[hy][hx] - vyH[hy - 1][hx]) +
                 C2C * (vyH[hy + 1][hx] - vyH[hy - 2][hx])) * RDX;           // dmy(vy)
            m = by * mA[4][ly][lx] + (by - 1.0f) * d; mA[4][ly][lx] = m;
            float dvy_dy = d + m;
            d = (C1C * (vxH[hy][hx] - vxH[hy][hx - 1]) +
                 C2C * (vxH[hy][hx + 1] - vxH[hy][hx - 2])) * RDX;           // dmx(vx)
            m = bx * mA[5][ly][lx] + (bx - 1.0f) * d; mA[5][ly][lx] = m;
            float dvx_dx = d + m;
            float lam = params[0 * FSTRIDE + gi];
            float lp2m = params[1 * FSTRIDE + gi];
            float nsyy = syyH[hy][hx] + DTC * (lp2m * dvy_dy + lam * dvx_dx);
            float nsxx = sxxH[hy][hx] + DTC * (lp2m * dvx_dx + lam * dvy_dy);
            d = (C1C * (vyH[hy][hx + 1] - vyH[hy][hx]) +
                 C2C * (vyH[hy][hx + 2] - vyH[hy][hx - 1])) * RDX;           // dpx(vy)
            m = bx * mA[6][ly][lx] + (bx - 1.0f) * d; mA[6][ly][lx] = m;
            float dvy_dx = d + m;
            d = (C1C * (vxH[hy + 1][hx] - vxH[hy][hx]) +
                 C2C * (vxH[hy + 2][hx] - vxH[hy - 1][hx])) * RDX;           // dpy(vx)
            m = by * mA[7][ly][lx] + (by - 1.0f) * d; mA[7][ly][lx] = m;
            float dvx_dy = d + m;
            float nsxy = sxyH[hy][hx] + DTC * params[2 * FSTRIDE + gi] * (dvy_dx + dvx_dy);
            syyH[hy][hx] = nsyy; sxxH[hy][hx] = nsxx; sxyH[hy][hx] = nsxy;
            if (ly < 2 || ly >= h - 2 || lx < 2 || lx >= w - 2) {
                astore(&gsyy[gi], nsyy);
                astore(&gsxx[gi], nsxx);
                astore(&gsxy[gi], nsxy);
            }
        }
        __builtin_amdgcn_s_waitcnt(0);
        __syncthreads();
        if (tid == 0)
            __hip_atomic_store(&flagS[blockIdx.x], (unsigned)(t + 1),
                               __ATOMIC_RELAXED, __HIP_MEMORY_SCOPE_AGENT);
    }
}

// ------------------------------ fallback path (R1, proven) ------------------

__global__ __launch_bounds__(256)
void vel_kernel(float* __restrict__ ws, const float* __restrict__ params,
                const float* __restrict__ bdec, const float* __restrict__ amps,
                const int* __restrict__ sloc, int t) {
    int x = blockIdx.x * 64 + threadIdx.x;
    int y = blockIdx.y * 4 + threadIdx.y;
    int s = blockIdx.z;
    if (x >= NXP) return;
    float* F = ws + (size_t)s * 13 * FSTRIDE;
    float* vy = F; float* vx = F + FSTRIDE;
    const float* syy = F + 2 * FSTRIDE;
    const float* sxx = F + 3 * FSTRIDE;
    const float* sxy = F + 4 * FSTRIDE;
    float* msyy_y = F + 9 * FSTRIDE;  float* msxy_x = F + 10 * FSTRIDE;
    float* msxy_y = F + 11 * FSTRIDE; float* msxx_x = F + 12 * FSTRIDE;
    float by = bdec[y], bx = bdec[NYP + x];
    int idx = y * PITCH + x;
    auto ldf2 = [&](const float* f, int yy, int xx) {
        return (yy >= 0 && yy < NYP && xx >= 0 && xx < NXP) ? f[yy * PITCH + xx] : 0.0f;
    };
    float buoy = params[3 * FSTRIDE + idx];
    float d, m;
    d = (C1C * (ldf2(syy,y+1,x) - ldf2(syy,y,x)) + C2C * (ldf2(syy,y+2,x) - ldf2(syy,y-1,x))) * RDX;
    m = by * msyy_y[idx] + (by - 1.0f) * d; msyy_y[idx] = m;
    float a1 = d + m;
    d = (C1C * (ldf2(sxy,y,x) - ldf2(sxy,y,x-1)) + C2C * (ldf2(sxy,y,x+1) - ldf2(sxy,y,x-2))) * RDX;
    m = bx * msxy_x[idx] + (bx - 1.0f) * d; msxy_x[idx] = m;
    float nvy = vy[idx] + DTC * buoy * (a1 + d + m);
    d = (C1C * (ldf2(sxy,y,x) - ldf2(sxy,y-1,x)) + C2C * (ldf2(sxy,y+1,x) - ldf2(sxy,y-2,x))) * RDX;
    m = by * msxy_y[idx] + (by - 1.0f) * d; msxy_y[idx] = m;
    float a2 = d + m;
    d = (C1C * (ldf2(sxx,y,x+1) - ldf2(sxx,y,x)) + C2C * (ldf2(sxx,y,x+2) - ldf2(sxx,y,x-1))) * RDX;
    m = bx * msxx_x[idx] + (bx - 1.0f) * d; msxx_x[idx] = m;
    float nvx = vx[idx] + DTC * buoy * (a2 + d + m);
    int sy = sloc[s * 2 + 0] + PML, sx = sloc[s * 2 + 1] + PML;
    if (y == sy && x == sx) nvy += amps[s * NT + t];
    vy[idx] = nvy; vx[idx] = nvx;
}

__global__ __launch_bounds__(256)
void str_kernel(float* __restrict__ ws, const float* __restrict__ params,
                const float* __restrict__ bdec, const int* __restrict__ rloc,
                float* __restrict__ out, int t) {
    int x = blockIdx.x * 64 + threadIdx.x;
    int y = blockIdx.y * 4 + threadIdx.y;
    int s = blockIdx.z;
    float* F = ws + (size_t)s * 13 * FSTRIDE;
    const float* vy = F; const float* vx = F + FSTRIDE;
    float* syy = F + 2 * FSTRIDE; float* sxx = F + 3 * FSTRIDE; float* sxy = F + 4 * FSTRIDE;
    float* mvyy = F + 5 * FSTRIDE; float* mvyx = F + 6 * FSTRIDE;
    float* mvxy = F + 7 * FSTRIDE; float* mvxx = F + 8 * FSTRIDE;
    if (blockIdx.x == 0 && blockIdx.y == 0) {
        int tid = threadIdx.y * 64 + threadIdx.x;
        if (tid < NREC) {
            int ry = rloc[(s * NREC + tid) * 2 + 0] + PML;
            int rx = rloc[(s * NREC + tid) * 2 + 1] + PML;
            out[(s * NREC + tid) * NT + t] = vy[ry * PITCH + rx];
        }
    }
    if (x >= NXP) return;
    auto ldf2 = [&](const float* f, int yy, int xx) {
        return (yy >= 0 && yy < NYP && xx >= 0 && xx < NXP) ? f[yy * PITCH + xx] : 0.0f;
    };
    float by = bdec[y], bx = bdec[NYP + x];
    int idx = y * PITCH + x;
    float lam = params[idx], lp2m = params[FSTRIDE + idx], muv = params[2 * FSTRIDE + idx];
    float d, m;
    d = (C1C * (ldf2(vy,y,x) - ldf2(vy,y-1,x)) + C2C * (ldf2(vy,y+1,x) - ldf2(vy,y-2,x))) * RDX;
    m = by * mvyy[idx] + (by - 1.0f) * d; mvyy[idx] = m;
    float dvy_dy = d + m;
    d = (C1C * (ldf2(vx,y,x) - ldf2(vx,y,x-1)) + C2C * (ldf2(vx,y,x+1) - ldf2(vx,y,x-2))) * RDX;
    m = bx * mvxx[idx] + (bx - 1.0f) * d; mvxx[idx] = m;
    float dvx_dx = d + m;
    syy[idx] += DTC * (lp2m * dvy_dy + lam * dvx_dx);
    sxx[idx] += DTC * (lp2m * dvx_dx + lam * dvy_dy);
    d = (C1C * (ldf2(vy,y,x+1) - ldf2(vy,y,x)) + C2C * (ldf2(vy,y,x+2) - ldf2(vy,y,x-1))) * RDX;
    m = bx * mvyx[idx] + (bx - 1.0f) * d; mvyx[idx] = m;
    float dvy_dx = d + m;
    d = (C1C * (ldf2(vx,y+1,x) - ldf2(vx,y,x)) + C2C * (ldf2(vx,y+2,x) - ldf2(vx,y-1,x))) * RDX;
    m = by * mvxy[idx] + (by - 1.0f) * d; mvxy[idx] = m;
    float dvx_dy = d + m;
    sxy[idx] += DTC * muv * (dvy_dx + dvx_dy);
}

// ----------------------------------------------------------------------------

extern "C" void kernel_launch(void* const* d_in, const int* in_sizes, int n_in,
                              void* d_out, int out_size, void* d_ws, size_t ws_size,
                              hipStream_t stream) {
    const float* lamb = (const float*)d_in[0];
    const float* mu   = (const float*)d_in[1];
    const float* buo  = (const float*)d_in[2];
    const float* amps = (const float*)d_in[3];
    const int*   sloc = (const int*)d_in[4];
    const int*   rloc = (const int*)d_in[5];
    float* out = (float*)d_out;

    float* wsf = (float*)d_ws;
    // layout: [flags 1024 u32][strips 10*FSTRIDE][params 4*FSTRIDE][bdec 680]
    unsigned* flags = (unsigned*)wsf;
    float* strips = wsf + 1024;
    float* params = wsf + 1024 + (size_t)10 * FSTRIDE;
    float* bdec   = wsf + 1024 + (size_t)14 * FSTRIDE;
    size_t needed = (size_t)(1024 + 14 * FSTRIDE + NYP + NXP) * sizeof(float);

    dim3 pib(256, 1, 1), pig((NXP + 255) / 256, NYP, 1);

    if (ws_size >= needed) {
        (void)hipMemsetAsync(wsf, 0, (size_t)(1024 + 10 * FSTRIDE) * sizeof(float), stream);
        init_params_kernel<<<pig, pib, 0, stream>>>(lamb, mu, buo, params);
        init_decay_kernel<<<(NYP + NXP + 255) / 256, 256, 0, stream>>>(bdec);
        void* args[] = {&strips, &params, &bdec, &amps, &sloc, &rloc, &out, &flags};
        (void)hipLaunchCooperativeKernel((void*)persist2_kernel, dim3(NSHOT * TX * TY),
                                         dim3(256), args, 0, stream);
    } else {
        float* statef = wsf + 64;
        float* paramf = wsf + 64 + (size_t)26 * FSTRIDE;
        float* bdecf  = wsf + 64 + (size_t)30 * FSTRIDE;
        (void)hipMemsetAsync(statef, 0, (size_t)26 * FSTRIDE * sizeof(float), stream);
        init_params_kernel<<<pig, pib, 0, stream>>>(lamb, mu, buo, paramf);
        init_decay_kernel<<<(NYP + NXP + 255) / 256, 256, 0, stream>>>(bdecf);
        dim3 blk(64, 4, 1), grd((NXP + 63) / 64, NYP / 4, NSHOT);
        for (int t = 0; t < NT; ++t) {
            vel_kernel<<<grd, blk, 0, stream>>>(statef, paramf, bdecf, amps, sloc, t);
            str_kernel<<<grd, blk, 0, stream>>>(statef, paramf, bdecf, rloc, out, t);
        }
    }
}

// Round 6
// 1090.465 us; speedup vs baseline: 5.6727x; 1.8413x over previous
//
#include <hip/hip_runtime.h>

// ---------------------------------------------------------------------------
// Elastic 2D velocity-stress staggered FD + C-PML, 2 shots, 128 steps.
// Round 6: persistent kernel, LDS-resident state, ONE exchange per step.
//  - Velocity computed redundantly on a +2 ring (consistent across blocks,
//    incl. its C-PML memories) -> stress phase needs no neighbor velocities.
//  - Only stress strips (3 fields, 4-wide boundary ring incl. corners) are
//    published per step, into parity (t&1) double-buffered global arrays.
//  - 8-neighbor flag wait (skew <= 1 step provable); poll latency hidden
//    behind the core-velocity compute which has no external dependency.
//  - Relaxed agent-scope atomics only; NO fences -> L2 stays warm.
// ---------------------------------------------------------------------------

#define NYI   300
#define NXI   300
#define PML   20
#define NYP   340
#define NXP   340
#define NT    128
#define DXC   5.0f
#define DTC   0.001f
#define NSHOT 2
#define NREC  32
#define C1C   (9.0f / 8.0f)
#define C2C   (-1.0f / 24.0f)
#define RDX   (1.0f / 5.0f)

#define PITCH   344
#define FSTRIDE (NYP * PITCH)

// tile grid per shot: 8 x 16 tiles
#define TX 8
#define TY 16
#define TW 43
#define TH 22
// LDS array dims (max tile + rings)
#define MH 30   // TH + 8 (stress ring4)
#define MW 52   // TW + 8 = 51 -> pad 52
#define VH 26   // TH + 4 (velocity ring2)
#define VW 48   // TW + 4 = 47 -> pad 48
#define IH 22
#define IW 44

__device__ __forceinline__ float aload(const float* p) {
    return __hip_atomic_load(p, __ATOMIC_RELAXED, __HIP_MEMORY_SCOPE_AGENT);
}
__device__ __forceinline__ void astore(float* p, float v) {
    __hip_atomic_store(p, v, __ATOMIC_RELAXED, __HIP_MEMORY_SCOPE_AGENT);
}

// params[0]=lam, [1]=lam+2mu, [2]=mu, [3]=buoyancy (edge-padded into PML)
__global__ void init_params_kernel(const float* __restrict__ lamb,
                                   const float* __restrict__ mu,
                                   const float* __restrict__ buo,
                                   float* __restrict__ params) {
    int x = blockIdx.x * blockDim.x + threadIdx.x;
    int y = blockIdx.y;
    if (x >= NXP || y >= NYP) return;
    int cy = y - PML; cy = cy < 0 ? 0 : (cy > NYI - 1 ? NYI - 1 : cy);
    int cx = x - PML; cx = cx < 0 ? 0 : (cx > NXI - 1 ? NXI - 1 : cx);
    float l = lamb[cy * NXI + cx];
    float m = mu[cy * NXI + cx];
    float b = buo[cy * NXI + cx];
    int idx = y * PITCH + x;
    params[0 * FSTRIDE + idx] = l;
    params[1 * FSTRIDE + idx] = l + 2.0f * m;
    params[2 * FSTRIDE + idx] = m;
    params[3 * FSTRIDE + idx] = b;
}

__global__ void init_decay_kernel(float* __restrict__ bdec) {
    int i = blockIdx.x * blockDim.x + threadIdx.x;
    if (i >= NYP + NXP) return;
    int idx = (i < NYP) ? i : i - NYP;
    float fx = (float)idx;
    float lo = fminf(fmaxf(((float)PML - fx) / (float)PML, 0.0f), 1.0f);
    float hi = fminf(fmaxf((fx - (float)(NYP - 1 - PML)) / (float)PML, 0.0f), 1.0f);
    float mx = fmaxf(lo, hi);
    float d0 = 3.0f * 2000.0f / (2.0f * (float)PML * DXC) * logf(1.0f / 1e-6f);
    bdec[i] = expf(-d0 * mx * mx * DTC);
}

__global__ __launch_bounds__(256)
void persist3_kernel(float* __restrict__ strips, const float* __restrict__ params,
                     const float* __restrict__ bdec, const float* __restrict__ amps,
                     const int* __restrict__ sloc, const int* __restrict__ rloc,
                     float* __restrict__ out, unsigned* __restrict__ flags) {
    __shared__ float syyR[MH][MW], sxxR[MH][MW], sxyR[MH][MW];
    __shared__ float vyR[VH][VW], vxR[VH][VW];
    __shared__ float mv0[VH][VW], mv1[VH][VW], mv2[VH][VW], mv3[VH][VW];
    __shared__ float ms0[IH][IW], ms1[IH][IW], ms2[IH][IW], ms3[IH][IW];
    __shared__ float buoL[VH][VW];
    __shared__ float lamL[IH][IW], lp2mL[IH][IW], muL[IH][IW];
    __shared__ float byL[VH], bxL[VW];

    const int tid = threadIdx.x;
    const int s = blockIdx.x >> 7, tile = blockIdx.x & 127;
    const int txi = tile & 7, tyi = tile >> 3;
    const int x0 = txi * TW, x1 = min(x0 + TW, NXP);
    const int y0 = tyi * TH, y1 = min(y0 + TH, NYP);
    const int w = x1 - x0, h = y1 - y0;

    // 8 neighbors (N,S,W,E + diagonals), lane tid<8 polls one each
    int nbId = -1;
    if (tid < 8) {
        const int dy8[8] = {-1, 1, 0, 0, -1, -1, 1, 1};
        const int dx8[8] = {0, 0, -1, 1, -1, 1, -1, 1};
        int nty = tyi + dy8[tid], ntx = txi + dx8[tid];
        if (nty >= 0 && nty < TY && ntx >= 0 && ntx < TX)
            nbId = (s << 7) + (nty << 3) + ntx;
    }

    // ---- zero LDS state; load params/decay into LDS ----
    for (int i = tid; i < MH * MW; i += 256) {
        int r = i / MW, c = i - r * MW;
        syyR[r][c] = 0.0f; sxxR[r][c] = 0.0f; sxyR[r][c] = 0.0f;
    }
    for (int i = tid; i < VH * VW; i += 256) {
        int r = i / VW, c = i - r * VW;
        vyR[r][c] = 0.0f; vxR[r][c] = 0.0f;
        mv0[r][c] = 0.0f; mv1[r][c] = 0.0f; mv2[r][c] = 0.0f; mv3[r][c] = 0.0f;
        buoL[r][c] = 0.0f;
    }
    for (int i = tid; i < IH * IW; i += 256) {
        int r = i / IW, c = i - r * IW;
        ms0[r][c] = 0.0f; ms1[r][c] = 0.0f; ms2[r][c] = 0.0f; ms3[r][c] = 0.0f;
    }
    if (tid < VH) {
        int y = y0 - 2 + tid; y = min(max(y, 0), NYP - 1);
        byL[tid] = bdec[y];
    } else if (tid >= 64 && tid < 64 + VW) {
        int i = tid - 64, x = x0 - 2 + i; x = min(max(x, 0), NXP - 1);
        bxL[i] = bdec[NYP + x];
    }
    __syncthreads();
    {
        int ry0v = max(y0 - 2, 0), ry1v = min(y1 + 2, NYP);
        int rx0v = max(x0 - 2, 0), rx1v = min(x1 + 2, NXP);
        int rh = ry1v - ry0v, rw = rx1v - rx0v;
        for (int i = tid; i < rh * rw; i += 256) {
            int r = i / rw, c = i - r * rw;
            int y = ry0v + r, x = rx0v + c;
            buoL[y - y0 + 2][x - x0 + 2] = params[3 * FSTRIDE + y * PITCH + x];
        }
        for (int i = tid; i < h * w; i += 256) {
            int r = i / w, c = i - r * w;
            int gi = (y0 + r) * PITCH + (x0 + c);
            lamL[r][c] = params[gi];
            lp2mL[r][c] = params[FSTRIDE + gi];
            muL[r][c] = params[2 * FSTRIDE + gi];
        }
    }

    const int sy = sloc[s * 2 + 0] + PML;
    const int sx = sloc[s * 2 + 1] + PML;

    bool hasRec = false; int recOff = 0, rvi = 0, rvj = 0;
    if (tid < NSHOT * NREC) {
        int rs = tid >> 5, rr = tid & 31;
        if (rs == s) {
            int ry = rloc[(rs * NREC + rr) * 2 + 0] + PML;
            int rx = rloc[(rs * NREC + rr) * 2 + 1] + PML;
            if (ry >= y0 && ry < y1 && rx >= x0 && rx < x1) {
                hasRec = true; recOff = (rs * NREC + rr) * NT;
                rvi = ry - y0 + 2; rvj = rx - x0 + 2;
            }
        }
    }
    __syncthreads();

    // region geometry
    const int vy0 = max(y0 - 2, 0), vy1 = min(y1 + 2, NYP);
    const int vx0 = max(x0 - 2, 0), vx1 = min(x1 + 2, NXP);
    const int cy0 = y0 + 2, cy1 = y1 - 2, cx0 = x0 + 2, cx1 = x1 - 2;
    const int cw = cx1 - cx0, ch = cy1 - cy0, nCore = cw * ch;
    const int W2 = vx1 - vx0;
    const int topH = cy0 - vy0, botH = vy1 - cy1;
    const int leftW = cx0 - vx0, rightW = vx1 - cx1;
    const int nTop = topH * W2, nBot = botH * W2;
    const int nLeft = ch * leftW, nRight = ch * rightW;
    const int nRing = nTop + nBot + nLeft + nRight;
    const int py0 = max(y0 - 4, 0), py1 = min(y1 + 4, NYP);
    const int px0 = max(x0 - 4, 0), px1 = min(x1 + 4, NXP);
    const int W4 = px1 - px0;
    const int ptH = y0 - py0, pbH = py1 - y1;
    const int plW = x0 - px0, prW = px1 - x1;
    const int nPT = ptH * W4, nPB = pbH * W4, nPL = h * plW, nPR = h * prW;
    const int nPull = nPT + nPB + nPL + nPR;

    auto doV = [&](int y, int x, float amp) {
        int hy = y - y0 + 4, hx = x - x0 + 4;
        int vi = y - y0 + 2, vj = x - x0 + 2;
        float by = byL[vi], bx = bxL[vj];
        float d1 = (C1C * (syyR[hy + 1][hx] - syyR[hy][hx]) +
                    C2C * (syyR[hy + 2][hx] - syyR[hy - 1][hx])) * RDX;   // dpy(syy)
        float m1 = by * mv0[vi][vj] + (by - 1.0f) * d1; mv0[vi][vj] = m1;
        float d2 = (C1C * (sxyR[hy][hx] - sxyR[hy][hx - 1]) +
                    C2C * (sxyR[hy][hx + 1] - sxyR[hy][hx - 2])) * RDX;   // dmx(sxy)
        float m2 = bx * mv1[vi][vj] + (bx - 1.0f) * d2; mv1[vi][vj] = m2;
        float nvy = vyR[vi][vj] + DTC * buoL[vi][vj] * (d1 + m1 + d2 + m2);
        float d3 = (C1C * (sxyR[hy][hx] - sxyR[hy - 1][hx]) +
                    C2C * (sxyR[hy + 1][hx] - sxyR[hy - 2][hx])) * RDX;   // dmy(sxy)
        float m3 = by * mv2[vi][vj] + (by - 1.0f) * d3; mv2[vi][vj] = m3;
        float d4 = (C1C * (sxxR[hy][hx + 1] - sxxR[hy][hx]) +
                    C2C * (sxxR[hy][hx + 2] - sxxR[hy][hx - 1])) * RDX;   // dpx(sxx)
        float m4 = bx * mv3[vi][vj] + (bx - 1.0f) * d4; mv3[vi][vj] = m4;
        float nvx = vxR[vi][vj] + DTC * buoL[vi][vj] * (d3 + m3 + d4 + m4);
        if (y == sy && x == sx) nvy += amp;
        vyR[vi][vj] = nvy; vxR[vi][vj] = nvx;
    };

    for (int t = 0; t < NT; ++t) {
        const float amp_t = amps[s * NT + t];

        // ---- A: velocity core (block-local; overlaps neighbor flag wait) ----
        for (int i = tid; i < nCore; i += 256) {
            int r = i / cw, c = i - r * cw;
            doV(cy0 + r, cx0 + c, amp_t);
        }
        if (tid < 8 && nbId >= 0) {
            while (__hip_atomic_load(&flags[nbId], __ATOMIC_RELAXED,
                                     __HIP_MEMORY_SCOPE_AGENT) < (unsigned)t)
                __builtin_amdgcn_s_sleep(1);
        }
        __syncthreads();

        // ---- B: pull stress halo (4-wide ring incl. corners), parity t^1 ----
        const float* gb = strips + (size_t)(((t ^ 1) & 1) * NSHOT + s) * 3 * FSTRIDE;
        for (int i = tid; i < nPull; i += 256) {
            int y, x, j = i;
            if (j < nPT)            { y = py0 + j / W4;  x = px0 + j % W4; }
            else { j -= nPT;
            if (j < nPB)            { y = y1 + j / W4;   x = px0 + j % W4; }
            else { j -= nPB;
            if (j < nPL)            { y = y0 + j / plW;  x = px0 + j % plW; }
            else { j -= nPL;          y = y0 + j / prW;  x = x1 + j % prW; } } }
            int gi = y * PITCH + x;
            int hy = y - y0 + 4, hx = x - x0 + 4;
            syyR[hy][hx] = aload(&gb[gi]);
            sxxR[hy][hx] = aload(&gb[FSTRIDE + gi]);
            sxyR[hy][hx] = aload(&gb[2 * FSTRIDE + gi]);
        }
        __syncthreads();

        // ---- C: velocity ring (+2 redundant, needs the pulled halo) ----
        for (int i = tid; i < nRing; i += 256) {
            int y, x, j = i;
            if (j < nTop)           { y = vy0 + j / W2;     x = vx0 + j % W2; }
            else { j -= nTop;
            if (j < nBot)           { y = cy1 + j / W2;     x = vx0 + j % W2; }
            else { j -= nBot;
            if (j < nLeft)          { y = cy0 + j / leftW;  x = vx0 + j % leftW; }
            else { j -= nLeft;        y = cy0 + j / rightW; x = cx1 + j % rightW; } } }
            doV(y, x, amp_t);
        }
        __syncthreads();

        if (hasRec) out[recOff + t] = vyR[rvi][rvj];

        // ---- D: stress interior + publish 4-wide boundary strips ----
        float* pb = strips + (size_t)((t & 1) * NSHOT + s) * 3 * FSTRIDE;
        for (int i = tid; i < h * w; i += 256) {
            int ly = i / w, lx = i - ly * w;
            int vi = ly + 2, vj = lx + 2;
            float by = byL[vi], bx = bxL[vj];
            float d, m;
            d = (C1C * (vyR[vi][vj] - vyR[vi - 1][vj]) +
                 C2C * (vyR[vi + 1][vj] - vyR[vi - 2][vj])) * RDX;        // dmy(vy)
            m = by * ms0[ly][lx] + (by - 1.0f) * d; ms0[ly][lx] = m;
            float dvy_dy = d + m;
            d = (C1C * (vxR[vi][vj] - vxR[vi][vj - 1]) +
                 C2C * (vxR[vi][vj + 1] - vxR[vi][vj - 2])) * RDX;        // dmx(vx)
            m = bx * ms1[ly][lx] + (bx - 1.0f) * d; ms1[ly][lx] = m;
            float dvx_dx = d + m;
            float nsyy = syyR[ly + 4][lx + 4] + DTC * (lp2mL[ly][lx] * dvy_dy + lamL[ly][lx] * dvx_dx);
            float nsxx = sxxR[ly + 4][lx + 4] + DTC * (lp2mL[ly][lx] * dvx_dx + lamL[ly][lx] * dvy_dy);
            d = (C1C * (vyR[vi][vj + 1] - vyR[vi][vj]) +
                 C2C * (vyR[vi][vj + 2] - vyR[vi][vj - 1])) * RDX;        // dpx(vy)
            m = bx * ms2[ly][lx] + (bx - 1.0f) * d; ms2[ly][lx] = m;
            float dvy_dx = d + m;
            d = (C1C * (vxR[vi + 1][vj] - vxR[vi][vj]) +
                 C2C * (vxR[vi + 2][vj] - vxR[vi - 1][vj])) * RDX;        // dpy(vx)
            m = by * ms3[ly][lx] + (by - 1.0f) * d; ms3[ly][lx] = m;
            float dvx_dy = d + m;
            float nsxy = sxyR[ly + 4][lx + 4] + DTC * muL[ly][lx] * (dvy_dx + dvx_dy);
            syyR[ly + 4][lx + 4] = nsyy;
            sxxR[ly + 4][lx + 4] = nsxx;
            sxyR[ly + 4][lx + 4] = nsxy;
            if (ly < 4 || ly >= h - 4 || lx < 4 || lx >= w - 4) {
                int gi = (y0 + ly) * PITCH + (x0 + lx);
                astore(&pb[gi], nsyy);
                astore(&pb[FSTRIDE + gi], nsxx);
                astore(&pb[2 * FSTRIDE + gi], nsxy);
            }
        }
        __builtin_amdgcn_s_waitcnt(0);
        __syncthreads();
        if (tid == 0)
            __hip_atomic_store(&flags[blockIdx.x], (unsigned)(t + 1),
                               __ATOMIC_RELAXED, __HIP_MEMORY_SCOPE_AGENT);
    }
}

// ------------------------------ fallback path (R1, proven) ------------------

__global__ __launch_bounds__(256)
void vel_kernel(float* __restrict__ ws, const float* __restrict__ params,
                const float* __restrict__ bdec, const float* __restrict__ amps,
                const int* __restrict__ sloc, int t) {
    int x = blockIdx.x * 64 + threadIdx.x;
    int y = blockIdx.y * 4 + threadIdx.y;
    int s = blockIdx.z;
    if (x >= NXP) return;
    float* F = ws + (size_t)s * 13 * FSTRIDE;
    float* vy = F; float* vx = F + FSTRIDE;
    const float* syy = F + 2 * FSTRIDE;
    const float* sxx = F + 3 * FSTRIDE;
    const float* sxy = F + 4 * FSTRIDE;
    float* msyy_y = F + 9 * FSTRIDE;  float* msxy_x = F + 10 * FSTRIDE;
    float* msxy_y = F + 11 * FSTRIDE; float* msxx_x = F + 12 * FSTRIDE;
    float by = bdec[y], bx = bdec[NYP + x];
    int idx = y * PITCH + x;
    auto ldf2 = [&](const float* f, int yy, int xx) {
        return (yy >= 0 && yy < NYP && xx >= 0 && xx < NXP) ? f[yy * PITCH + xx] : 0.0f;
    };
    float buoy = params[3 * FSTRIDE + idx];
    float d, m;
    d = (C1C * (ldf2(syy,y+1,x) - ldf2(syy,y,x)) + C2C * (ldf2(syy,y+2,x) - ldf2(syy,y-1,x))) * RDX;
    m = by * msyy_y[idx] + (by - 1.0f) * d; msyy_y[idx] = m;
    float a1 = d + m;
    d = (C1C * (ldf2(sxy,y,x) - ldf2(sxy,y,x-1)) + C2C * (ldf2(sxy,y,x+1) - ldf2(sxy,y,x-2))) * RDX;
    m = bx * msxy_x[idx] + (bx - 1.0f) * d; msxy_x[idx] = m;
    float nvy = vy[idx] + DTC * buoy * (a1 + d + m);
    d = (C1C * (ldf2(sxy,y,x) - ldf2(sxy,y-1,x)) + C2C * (ldf2(sxy,y+1,x) - ldf2(sxy,y-2,x))) * RDX;
    m = by * msxy_y[idx] + (by - 1.0f) * d; msxy_y[idx] = m;
    float a2 = d + m;
    d = (C1C * (ldf2(sxx,y,x+1) - ldf2(sxx,y,x)) + C2C * (ldf2(sxx,y,x+2) - ldf2(sxx,y,x-1))) * RDX;
    m = bx * msxx_x[idx] + (bx - 1.0f) * d; msxx_x[idx] = m;
    float nvx = vx[idx] + DTC * buoy * (a2 + d + m);
    int sy = sloc[s * 2 + 0] + PML, sx = sloc[s * 2 + 1] + PML;
    if (y == sy && x == sx) nvy += amps[s * NT + t];
    vy[idx] = nvy; vx[idx] = nvx;
}

__global__ __launch_bounds__(256)
void str_kernel(float* __restrict__ ws, const float* __restrict__ params,
                const float* __restrict__ bdec, const int* __restrict__ rloc,
                float* __restrict__ out, int t) {
    int x = blockIdx.x * 64 + threadIdx.x;
    int y = blockIdx.y * 4 + threadIdx.y;
    int s = blockIdx.z;
    float* F = ws + (size_t)s * 13 * FSTRIDE;
    const float* vy = F; const float* vx = F + FSTRIDE;
    float* syy = F + 2 * FSTRIDE; float* sxx = F + 3 * FSTRIDE; float* sxy = F + 4 * FSTRIDE;
    float* mvyy = F + 5 * FSTRIDE; float* mvyx = F + 6 * FSTRIDE;
    float* mvxy = F + 7 * FSTRIDE; float* mvxx = F + 8 * FSTRIDE;
    if (blockIdx.x == 0 && blockIdx.y == 0) {
        int tid = threadIdx.y * 64 + threadIdx.x;
        if (tid < NREC) {
            int ry = rloc[(s * NREC + tid) * 2 + 0] + PML;
            int rx = rloc[(s * NREC + tid) * 2 + 1] + PML;
            out[(s * NREC + tid) * NT + t] = vy[ry * PITCH + rx];
        }
    }
    if (x >= NXP) return;
    auto ldf2 = [&](const float* f, int yy, int xx) {
        return (yy >= 0 && yy < NYP && xx >= 0 && xx < NXP) ? f[yy * PITCH + xx] : 0.0f;
    };
    float by = bdec[y], bx = bdec[NYP + x];
    int idx = y * PITCH + x;
    float lam = params[idx], lp2m = params[FSTRIDE + idx], muv = params[2 * FSTRIDE + idx];
    float d, m;
    d = (C1C * (ldf2(vy,y,x) - ldf2(vy,y-1,x)) + C2C * (ldf2(vy,y+1,x) - ldf2(vy,y-2,x))) * RDX;
    m = by * mvyy[idx] + (by - 1.0f) * d; mvyy[idx] = m;
    float dvy_dy = d + m;
    d = (C1C * (ldf2(vx,y,x) - ldf2(vx,y,x-1)) + C2C * (ldf2(vx,y,x+1) - ldf2(vx,y,x-2))) * RDX;
    m = bx * mvxx[idx] + (bx - 1.0f) * d; mvxx[idx] = m;
    float dvx_dx = d + m;
    syy[idx] += DTC * (lp2m * dvy_dy + lam * dvx_dx);
    sxx[idx] += DTC * (lp2m * dvx_dx + lam * dvy_dy);
    d = (C1C * (ldf2(vy,y,x+1) - ldf2(vy,y,x)) + C2C * (ldf2(vy,y,x+2) - ldf2(vy,y,x-1))) * RDX;
    m = bx * mvyx[idx] + (bx - 1.0f) * d; mvyx[idx] = m;
    float dvy_dx = d + m;
    d = (C1C * (ldf2(vx,y+1,x) - ldf2(vx,y,x)) + C2C * (ldf2(vx,y+2,x) - ldf2(vx,y-1,x))) * RDX;
    m = by * mvxy[idx] + (by - 1.0f) * d; mvxy[idx] = m;
    float dvx_dy = d + m;
    sxy[idx] += DTC * muv * (dvy_dx + dvx_dy);
}

// ----------------------------------------------------------------------------

extern "C" void kernel_launch(void* const* d_in, const int* in_sizes, int n_in,
                              void* d_out, int out_size, void* d_ws, size_t ws_size,
                              hipStream_t stream) {
    const float* lamb = (const float*)d_in[0];
    const float* mu   = (const float*)d_in[1];
    const float* buo  = (const float*)d_in[2];
    const float* amps = (const float*)d_in[3];
    const int*   sloc = (const int*)d_in[4];
    const int*   rloc = (const int*)d_in[5];
    float* out = (float*)d_out;

    float* wsf = (float*)d_ws;
    // layout: [flags 512 u32][strips 12*FSTRIDE (2 parities x 2 shots x 3 fields)]
    //         [params 4*FSTRIDE][bdec 680]
    unsigned* flags = (unsigned*)wsf;
    float* strips = wsf + 512;
    float* params = wsf + 512 + (size_t)12 * FSTRIDE;
    float* bdec   = wsf + 512 + (size_t)16 * FSTRIDE;
    size_t needed = (size_t)(512 + 16 * FSTRIDE + NYP + NXP) * sizeof(float);

    dim3 pib(256, 1, 1), pig((NXP + 255) / 256, NYP, 1);

    if (ws_size >= needed) {
        (void)hipMemsetAsync(wsf, 0, (size_t)(512 + 12 * FSTRIDE) * sizeof(float), stream);
        init_params_kernel<<<pig, pib, 0, stream>>>(lamb, mu, buo, params);
        init_decay_kernel<<<(NYP + NXP + 255) / 256, 256, 0, stream>>>(bdec);
        void* args[] = {&strips, &params, &bdec, &amps, &sloc, &rloc, &out, &flags};
        (void)hipLaunchCooperativeKernel((void*)persist3_kernel, dim3(NSHOT * TX * TY),
                                         dim3(256), args, 0, stream);
    } else {
        float* statef = wsf + 64;
        float* paramf = wsf + 64 + (size_t)26 * FSTRIDE;
        float* bdecf  = wsf + 64 + (size_t)30 * FSTRIDE;
        (void)hipMemsetAsync(statef, 0, (size_t)26 * FSTRIDE * sizeof(float), stream);
        init_params_kernel<<<pig, pib, 0, stream>>>(lamb, mu, buo, paramf);
        init_decay_kernel<<<(NYP + NXP + 255) / 256, 256, 0, stream>>>(bdecf);
        dim3 blk(64, 4, 1), grd((NXP + 63) / 64, NYP / 4, NSHOT);
        for (int t = 0; t < NT; ++t) {
            vel_kernel<<<grd, blk, 0, stream>>>(statef, paramf, bdecf, amps, sloc, t);
            str_kernel<<<grd, blk, 0, stream>>>(statef, paramf, bdecf, rloc, out, t);
        }
    }
}

// Round 7
// 1039.015 us; speedup vs baseline: 5.9536x; 1.0495x over previous
//
#include <hip/hip_runtime.h>

// ---------------------------------------------------------------------------
// Elastic 2D velocity-stress staggered FD + C-PML, 2 shots, 128 steps.
// Round 7: persistent kernel, LDS-resident state, ONE exchange per step,
// TAG-IN-DATA sync: each published strip cell is an 8-byte (value, step-tag)
// relaxed agent-scope atomic. No flags, no vmcnt drain, no fences -> the
// publish->consume chain is one store->load round trip, pipelined per cell.
//  - Velocity computed redundantly on a +2 ring -> stress needs no neighbor V.
//  - Stress split boundary-first: D1 (depth<4) computes+publishes immediately,
//    D2 interior runs off the critical path.
//  - Parity (t&1) double-buffered strips; skew<=1 induction as R6.
// ---------------------------------------------------------------------------

typedef unsigned long long ull;

#define NYI   300
#define NXI   300
#define PML   20
#define NYP   340
#define NXP   340
#define NT    128
#define DXC   5.0f
#define DTC   0.001f
#define NSHOT 2
#define NREC  32
#define C1C   (9.0f / 8.0f)
#define C2C   (-1.0f / 24.0f)
#define RDX   (1.0f / 5.0f)

#define PITCH   344
#define FSTRIDE (NYP * PITCH)

// tile grid per shot: 8 x 16 tiles
#define TX 8
#define TY 16
#define TW 43
#define TH 22
#define MH 30   // TH + 8 (stress ring4)
#define MW 52
#define VH 26   // TH + 4 (velocity ring2)
#define VW 48
#define IH 22
#define IW 44

__device__ __forceinline__ float pullv(const ull* p, unsigned want) {
    ull u = __hip_atomic_load(p, __ATOMIC_RELAXED, __HIP_MEMORY_SCOPE_AGENT);
    while ((unsigned)(u >> 32) != want) {
        __builtin_amdgcn_s_sleep(1);
        u = __hip_atomic_load(p, __ATOMIC_RELAXED, __HIP_MEMORY_SCOPE_AGENT);
    }
    return __uint_as_float((unsigned)(u & 0xffffffffull));
}
__device__ __forceinline__ void pushv(ull* p, float v, unsigned tag) {
    ull u = ((ull)tag << 32) | (ull)__float_as_uint(v);
    __hip_atomic_store(p, u, __ATOMIC_RELAXED, __HIP_MEMORY_SCOPE_AGENT);
}

// params[0]=lam, [1]=lam+2mu, [2]=mu, [3]=buoyancy (edge-padded into PML)
__global__ void init_params_kernel(const float* __restrict__ lamb,
                                   const float* __restrict__ mu,
                                   const float* __restrict__ buo,
                                   float* __restrict__ params) {
    int x = blockIdx.x * blockDim.x + threadIdx.x;
    int y = blockIdx.y;
    if (x >= NXP || y >= NYP) return;
    int cy = y - PML; cy = cy < 0 ? 0 : (cy > NYI - 1 ? NYI - 1 : cy);
    int cx = x - PML; cx = cx < 0 ? 0 : (cx > NXI - 1 ? NXI - 1 : cx);
    float l = lamb[cy * NXI + cx];
    float m = mu[cy * NXI + cx];
    float b = buo[cy * NXI + cx];
    int idx = y * PITCH + x;
    params[0 * FSTRIDE + idx] = l;
    params[1 * FSTRIDE + idx] = l + 2.0f * m;
    params[2 * FSTRIDE + idx] = m;
    params[3 * FSTRIDE + idx] = b;
}

__global__ void init_decay_kernel(float* __restrict__ bdec) {
    int i = blockIdx.x * blockDim.x + threadIdx.x;
    if (i >= NYP + NXP) return;
    int idx = (i < NYP) ? i : i - NYP;
    float fx = (float)idx;
    float lo = fminf(fmaxf(((float)PML - fx) / (float)PML, 0.0f), 1.0f);
    float hi = fminf(fmaxf((fx - (float)(NYP - 1 - PML)) / (float)PML, 0.0f), 1.0f);
    float mx = fmaxf(lo, hi);
    float d0 = 3.0f * 2000.0f / (2.0f * (float)PML * DXC) * logf(1.0f / 1e-6f);
    bdec[i] = expf(-d0 * mx * mx * DTC);
}

__global__ __launch_bounds__(256)
void persist4_kernel(ull* __restrict__ strips, const float* __restrict__ params,
                     const float* __restrict__ bdec, const float* __restrict__ amps,
                     const int* __restrict__ sloc, const int* __restrict__ rloc,
                     float* __restrict__ out) {
    __shared__ float syyR[MH][MW], sxxR[MH][MW], sxyR[MH][MW];
    __shared__ float vyR[VH][VW], vxR[VH][VW];
    __shared__ float mv0[VH][VW], mv1[VH][VW], mv2[VH][VW], mv3[VH][VW];
    __shared__ float ms0[IH][IW], ms1[IH][IW], ms2[IH][IW], ms3[IH][IW];
    __shared__ float buoL[VH][VW];
    __shared__ float lamL[IH][IW], lp2mL[IH][IW], muL[IH][IW];
    __shared__ float byL[VH], bxL[VW];

    const int tid = threadIdx.x;
    const int s = blockIdx.x >> 7, tile = blockIdx.x & 127;
    const int txi = tile & 7, tyi = tile >> 3;
    const int x0 = txi * TW, x1 = min(x0 + TW, NXP);
    const int y0 = tyi * TH, y1 = min(y0 + TH, NYP);
    const int w = x1 - x0, h = y1 - y0;

    // ---- zero LDS state; load params/decay into LDS ----
    for (int i = tid; i < MH * MW; i += 256) {
        int r = i / MW, c = i - r * MW;
        syyR[r][c] = 0.0f; sxxR[r][c] = 0.0f; sxyR[r][c] = 0.0f;
    }
    for (int i = tid; i < VH * VW; i += 256) {
        int r = i / VW, c = i - r * VW;
        vyR[r][c] = 0.0f; vxR[r][c] = 0.0f;
        mv0[r][c] = 0.0f; mv1[r][c] = 0.0f; mv2[r][c] = 0.0f; mv3[r][c] = 0.0f;
        buoL[r][c] = 0.0f;
    }
    for (int i = tid; i < IH * IW; i += 256) {
        int r = i / IW, c = i - r * IW;
        ms0[r][c] = 0.0f; ms1[r][c] = 0.0f; ms2[r][c] = 0.0f; ms3[r][c] = 0.0f;
    }
    if (tid < VH) {
        int y = y0 - 2 + tid; y = min(max(y, 0), NYP - 1);
        byL[tid] = bdec[y];
    } else if (tid >= 64 && tid < 64 + VW) {
        int i = tid - 64, x = x0 - 2 + i; x = min(max(x, 0), NXP - 1);
        bxL[i] = bdec[NYP + x];
    }
    __syncthreads();
    {
        int ry0v = max(y0 - 2, 0), ry1v = min(y1 + 2, NYP);
        int rx0v = max(x0 - 2, 0), rx1v = min(x1 + 2, NXP);
        int rh = ry1v - ry0v, rw = rx1v - rx0v;
        for (int i = tid; i < rh * rw; i += 256) {
            int r = i / rw, c = i - r * rw;
            int y = ry0v + r, x = rx0v + c;
            buoL[y - y0 + 2][x - x0 + 2] = params[3 * FSTRIDE + y * PITCH + x];
        }
        for (int i = tid; i < h * w; i += 256) {
            int r = i / w, c = i - r * w;
            int gi = (y0 + r) * PITCH + (x0 + c);
            lamL[r][c] = params[gi];
            lp2mL[r][c] = params[FSTRIDE + gi];
            muL[r][c] = params[2 * FSTRIDE + gi];
        }
    }

    const int sy = sloc[s * 2 + 0] + PML;
    const int sx = sloc[s * 2 + 1] + PML;

    bool hasRec = false; int recOff = 0, rvi = 0, rvj = 0;
    if (tid < NSHOT * NREC) {
        int rs = tid >> 5, rr = tid & 31;
        if (rs == s) {
            int ry = rloc[(rs * NREC + rr) * 2 + 0] + PML;
            int rx = rloc[(rs * NREC + rr) * 2 + 1] + PML;
            if (ry >= y0 && ry < y1 && rx >= x0 && rx < x1) {
                hasRec = true; recOff = (rs * NREC + rr) * NT;
                rvi = ry - y0 + 2; rvj = rx - x0 + 2;
            }
        }
    }
    __syncthreads();

    // region geometry (identical to R6, validated)
    const int vy0 = max(y0 - 2, 0), vy1 = min(y1 + 2, NYP);
    const int vx0 = max(x0 - 2, 0), vx1 = min(x1 + 2, NXP);
    const int cy0 = y0 + 2, cy1 = y1 - 2, cx0 = x0 + 2, cx1 = x1 - 2;
    const int cw = cx1 - cx0, ch = cy1 - cy0, nCore = cw * ch;
    const int W2 = vx1 - vx0;
    const int topH = cy0 - vy0, botH = vy1 - cy1;
    const int leftW = cx0 - vx0, rightW = vx1 - cx1;
    const int nTop = topH * W2, nBot = botH * W2;
    const int nLeft = ch * leftW, nRight = ch * rightW;
    const int nRing = nTop + nBot + nLeft + nRight;
    const int py0 = max(y0 - 4, 0), py1 = min(y1 + 4, NYP);
    const int px0 = max(x0 - 4, 0), px1 = min(x1 + 4, NXP);
    const int W4 = px1 - px0;
    const int ptH = y0 - py0, pbH = py1 - y1;
    const int plW = x0 - px0, prW = px1 - x1;
    const int nPT = ptH * W4, nPB = pbH * W4, nPL = h * plW, nPR = h * prW;
    const int nPull = nPT + nPB + nPL + nPR;

    auto doV = [&](int y, int x, float amp) {
        int hy = y - y0 + 4, hx = x - x0 + 4;
        int vi = y - y0 + 2, vj = x - x0 + 2;
        float by = byL[vi], bx = bxL[vj];
        float d1 = (C1C * (syyR[hy + 1][hx] - syyR[hy][hx]) +
                    C2C * (syyR[hy + 2][hx] - syyR[hy - 1][hx])) * RDX;   // dpy(syy)
        float m1 = by * mv0[vi][vj] + (by - 1.0f) * d1; mv0[vi][vj] = m1;
        float d2 = (C1C * (sxyR[hy][hx] - sxyR[hy][hx - 1]) +
                    C2C * (sxyR[hy][hx + 1] - sxyR[hy][hx - 2])) * RDX;   // dmx(sxy)
        float m2 = bx * mv1[vi][vj] + (bx - 1.0f) * d2; mv1[vi][vj] = m2;
        float nvy = vyR[vi][vj] + DTC * buoL[vi][vj] * (d1 + m1 + d2 + m2);
        float d3 = (C1C * (sxyR[hy][hx] - sxyR[hy - 1][hx]) +
                    C2C * (sxyR[hy + 1][hx] - sxyR[hy - 2][hx])) * RDX;   // dmy(sxy)
        float m3 = by * mv2[vi][vj] + (by - 1.0f) * d3; mv2[vi][vj] = m3;
        float d4 = (C1C * (sxxR[hy][hx + 1] - sxxR[hy][hx]) +
                    C2C * (sxxR[hy][hx + 2] - sxxR[hy][hx - 1])) * RDX;   // dpx(sxx)
        float m4 = bx * mv3[vi][vj] + (bx - 1.0f) * d4; mv3[vi][vj] = m4;
        float nvx = vxR[vi][vj] + DTC * buoL[vi][vj] * (d3 + m3 + d4 + m4);
        if (y == sy && x == sx) nvy += amp;
        vyR[vi][vj] = nvy; vxR[vi][vj] = nvx;
    };

    auto doS = [&](int ly, int lx, ull* qA, ull* qB, ull* qC, unsigned tag, bool pub) {
        int vi = ly + 2, vj = lx + 2;
        float by = byL[vi], bx = bxL[vj];
        float d, m;
        d = (C1C * (vyR[vi][vj] - vyR[vi - 1][vj]) +
             C2C * (vyR[vi + 1][vj] - vyR[vi - 2][vj])) * RDX;            // dmy(vy)
        m = by * ms0[ly][lx] + (by - 1.0f) * d; ms0[ly][lx] = m;
        float dvy_dy = d + m;
        d = (C1C * (vxR[vi][vj] - vxR[vi][vj - 1]) +
             C2C * (vxR[vi][vj + 1] - vxR[vi][vj - 2])) * RDX;            // dmx(vx)
        m = bx * ms1[ly][lx] + (bx - 1.0f) * d; ms1[ly][lx] = m;
        float dvx_dx = d + m;
        float nsyy = syyR[ly + 4][lx + 4] + DTC * (lp2mL[ly][lx] * dvy_dy + lamL[ly][lx] * dvx_dx);
        float nsxx = sxxR[ly + 4][lx + 4] + DTC * (lp2mL[ly][lx] * dvx_dx + lamL[ly][lx] * dvy_dy);
        d = (C1C * (vyR[vi][vj + 1] - vyR[vi][vj]) +
             C2C * (vyR[vi][vj + 2] - vyR[vi][vj - 1])) * RDX;            // dpx(vy)
        m = bx * ms2[ly][lx] + (bx - 1.0f) * d; ms2[ly][lx] = m;
        float dvy_dx = d + m;
        d = (C1C * (vxR[vi + 1][vj] - vxR[vi][vj]) +
             C2C * (vxR[vi + 2][vj] - vxR[vi - 1][vj])) * RDX;            // dpy(vx)
        m = by * ms3[ly][lx] + (by - 1.0f) * d; ms3[ly][lx] = m;
        float dvx_dy = d + m;
        float nsxy = sxyR[ly + 4][lx + 4] + DTC * muL[ly][lx] * (dvy_dx + dvx_dy);
        syyR[ly + 4][lx + 4] = nsyy;
        sxxR[ly + 4][lx + 4] = nsxx;
        sxyR[ly + 4][lx + 4] = nsxy;
        if (pub) {
            int gi = (y0 + ly) * PITCH + (x0 + lx);
            pushv(&qA[gi], nsyy, tag);
            pushv(&qB[gi], nsxx, tag);
            pushv(&qC[gi], nsxy, tag);
        }
    };

    for (int t = 0; t < NT; ++t) {
        const float amp_t = amps[s * NT + t];

        // ---- A: velocity core (block-local; runs while neighbor data lands) ----
        for (int i = tid; i < nCore; i += 256) {
            int r = i / cw, c = i - r * cw;
            doV(cy0 + r, cx0 + c, amp_t);
        }

        // ---- B: pull stress halo with per-cell tag polls (want tag == t) ----
        {
            const ull* bb = strips + (size_t)(((t ^ 1) & 1) * NSHOT + s) * 3 * FSTRIDE;
            const ull* pA = bb;
            const ull* pB = bb + FSTRIDE;
            const ull* pC = bb + 2 * FSTRIDE;
            for (int i = tid; i < nPull; i += 256) {
                int y, x, j = i;
                if (j < nPT)            { y = py0 + j / W4;  x = px0 + j % W4; }
                else { j -= nPT;
                if (j < nPB)            { y = y1 + j / W4;   x = px0 + j % W4; }
                else { j -= nPB;
                if (j < nPL)            { y = y0 + j / plW;  x = px0 + j % plW; }
                else { j -= nPL;          y = y0 + j / prW;  x = x1 + j % prW; } } }
                int gi = y * PITCH + x;
                int hy = y - y0 + 4, hx = x - x0 + 4;
                syyR[hy][hx] = pullv(&pA[gi], (unsigned)t);
                sxxR[hy][hx] = pullv(&pB[gi], (unsigned)t);
                sxyR[hy][hx] = pullv(&pC[gi], (unsigned)t);
            }
        }
        __syncthreads();

        // ---- C: velocity ring (+2 redundant, needs the pulled halo) ----
        for (int i = tid; i < nRing; i += 256) {
            int y, x, j = i;
            if (j < nTop)           { y = vy0 + j / W2;     x = vx0 + j % W2; }
            else { j -= nTop;
            if (j < nBot)           { y = cy1 + j / W2;     x = vx0 + j % W2; }
            else { j -= nBot;
            if (j < nLeft)          { y = cy0 + j / leftW;  x = vx0 + j % leftW; }
            else { j -= nLeft;        y = cy0 + j / rightW; x = cx1 + j % rightW; } } }
            doV(y, x, amp_t);
        }
        __syncthreads();

        if (hasRec) out[recOff + t] = vyR[rvi][rvj];

        // ---- D1: boundary stress (depth<4), publish immediately (tag t+1) ----
        {
            ull* pb = strips + (size_t)((t & 1) * NSHOT + s) * 3 * FSTRIDE;
            ull* qA = pb;
            ull* qB = pb + FSTRIDE;
            ull* qC = pb + 2 * FSTRIDE;
            const unsigned tag = (unsigned)(t + 1);
            const int midH = h - 8;
            const int nT4 = 4 * w, nB4 = 4 * w, nL4 = midH * 4;
            const int nD1 = nT4 + nB4 + 2 * nL4;
            for (int i = tid; i < nD1; i += 256) {
                int ly, lx, j = i;
                if (j < nT4)      { ly = j / w;           lx = j - (j / w) * w; }
                else { j -= nT4;
                if (j < nB4)      { ly = h - 4 + j / w;   lx = j - (j / w) * w; }
                else { j -= nB4;
                if (j < nL4)      { ly = 4 + (j >> 2);    lx = j & 3; }
                else { j -= nL4;    ly = 4 + (j >> 2);    lx = w - 4 + (j & 3); } } }
                doS(ly, lx, qA, qB, qC, tag, true);
            }
            // ---- D2: interior stress (off the inter-block critical path) ----
            const int w8 = w - 8, nD2 = midH * w8;
            for (int i = tid; i < nD2; i += 256) {
                int r = i / w8, c = i - r * w8;
                doS(4 + r, 4 + c, qA, qB, qC, 0u, false);
            }
        }
        __syncthreads();
    }
}

// ------------------------------ fallback path (R1, proven) ------------------

__global__ __launch_bounds__(256)
void vel_kernel(float* __restrict__ ws, const float* __restrict__ params,
                const float* __restrict__ bdec, const float* __restrict__ amps,
                const int* __restrict__ sloc, int t) {
    int x = blockIdx.x * 64 + threadIdx.x;
    int y = blockIdx.y * 4 + threadIdx.y;
    int s = blockIdx.z;
    if (x >= NXP) return;
    float* F = ws + (size_t)s * 13 * FSTRIDE;
    float* vy = F; float* vx = F + FSTRIDE;
    const float* syy = F + 2 * FSTRIDE;
    const float* sxx = F + 3 * FSTRIDE;
    const float* sxy = F + 4 * FSTRIDE;
    float* msyy_y = F + 9 * FSTRIDE;  float* msxy_x = F + 10 * FSTRIDE;
    float* msxy_y = F + 11 * FSTRIDE; float* msxx_x = F + 12 * FSTRIDE;
    float by = bdec[y], bx = bdec[NYP + x];
    int idx = y * PITCH + x;
    auto ldf2 = [&](const float* f, int yy, int xx) {
        return (yy >= 0 && yy < NYP && xx >= 0 && xx < NXP) ? f[yy * PITCH + xx] : 0.0f;
    };
    float buoy = params[3 * FSTRIDE + idx];
    float d, m;
    d = (C1C * (ldf2(syy,y+1,x) - ldf2(syy,y,x)) + C2C * (ldf2(syy,y+2,x) - ldf2(syy,y-1,x))) * RDX;
    m = by * msyy_y[idx] + (by - 1.0f) * d; msyy_y[idx] = m;
    float a1 = d + m;
    d = (C1C * (ldf2(sxy,y,x) - ldf2(sxy,y,x-1)) + C2C * (ldf2(sxy,y,x+1) - ldf2(sxy,y,x-2))) * RDX;
    m = bx * msxy_x[idx] + (bx - 1.0f) * d; msxy_x[idx] = m;
    float nvy = vy[idx] + DTC * buoy * (a1 + d + m);
    d = (C1C * (ldf2(sxy,y,x) - ldf2(sxy,y-1,x)) + C2C * (ldf2(sxy,y+1,x) - ldf2(sxy,y-2,x))) * RDX;
    m = by * msxy_y[idx] + (by - 1.0f) * d; msxy_y[idx] = m;
    float a2 = d + m;
    d = (C1C * (ldf2(sxx,y,x+1) - ldf2(sxx,y,x)) + C2C * (ldf2(sxx,y,x+2) - ldf2(sxx,y,x-1))) * RDX;
    m = bx * msxx_x[idx] + (bx - 1.0f) * d; msxx_x[idx] = m;
    float nvx = vx[idx] + DTC * buoy * (a2 + d + m);
    int sy = sloc[s * 2 + 0] + PML, sx = sloc[s * 2 + 1] + PML;
    if (y == sy && x == sx) nvy += amps[s * NT + t];
    vy[idx] = nvy; vx[idx] = nvx;
}

__global__ __launch_bounds__(256)
void str_kernel(float* __restrict__ ws, const float* __restrict__ params,
                const float* __restrict__ bdec, const int* __restrict__ rloc,
                float* __restrict__ out, int t) {
    int x = blockIdx.x * 64 + threadIdx.x;
    int y = blockIdx.y * 4 + threadIdx.y;
    int s = blockIdx.z;
    float* F = ws + (size_t)s * 13 * FSTRIDE;
    const float* vy = F; const float* vx = F + FSTRIDE;
    float* syy = F + 2 * FSTRIDE; float* sxx = F + 3 * FSTRIDE; float* sxy = F + 4 * FSTRIDE;
    float* mvyy = F + 5 * FSTRIDE; float* mvyx = F + 6 * FSTRIDE;
    float* mvxy = F + 7 * FSTRIDE; float* mvxx = F + 8 * FSTRIDE;
    if (blockIdx.x == 0 && blockIdx.y == 0) {
        int tid = threadIdx.y * 64 + threadIdx.x;
        if (tid < NREC) {
            int ry = rloc[(s * NREC + tid) * 2 + 0] + PML;
            int rx = rloc[(s * NREC + tid) * 2 + 1] + PML;
            out[(s * NREC + tid) * NT + t] = vy[ry * PITCH + rx];
        }
    }
    if (x >= NXP) return;
    auto ldf2 = [&](const float* f, int yy, int xx) {
        return (yy >= 0 && yy < NYP && xx >= 0 && xx < NXP) ? f[yy * PITCH + xx] : 0.0f;
    };
    float by = bdec[y], bx = bdec[NYP + x];
    int idx = y * PITCH + x;
    float lam = params[idx], lp2m = params[FSTRIDE + idx], muv = params[2 * FSTRIDE + idx];
    float d, m;
    d = (C1C * (ldf2(vy,y,x) - ldf2(vy,y-1,x)) + C2C * (ldf2(vy,y+1,x) - ldf2(vy,y-2,x))) * RDX;
    m = by * mvyy[idx] + (by - 1.0f) * d; mvyy[idx] = m;
    float dvy_dy = d + m;
    d = (C1C * (ldf2(vx,y,x) - ldf2(vx,y,x-1)) + C2C * (ldf2(vx,y,x+1) - ldf2(vx,y,x-2))) * RDX;
    m = bx * mvxx[idx] + (bx - 1.0f) * d; mvxx[idx] = m;
    float dvx_dx = d + m;
    syy[idx] += DTC * (lp2m * dvy_dy + lam * dvx_dx);
    sxx[idx] += DTC * (lp2m * dvx_dx + lam * dvy_dy);
    d = (C1C * (ldf2(vy,y,x+1) - ldf2(vy,y,x)) + C2C * (ldf2(vy,y,x+2) - ldf2(vy,y,x-1))) * RDX;
    m = bx * mvyx[idx] + (bx - 1.0f) * d; mvyx[idx] = m;
    float dvy_dx = d + m;
    d = (C1C * (ldf2(vx,y+1,x) - ldf2(vx,y,x)) + C2C * (ldf2(vx,y+2,x) - ldf2(vx,y-1,x))) * RDX;
    m = by * mvxy[idx] + (by - 1.0f) * d; mvxy[idx] = m;
    float dvx_dy = d + m;
    sxy[idx] += DTC * muv * (dvy_dx + dvx_dy);
}

// ----------------------------------------------------------------------------

extern "C" void kernel_launch(void* const* d_in, const int* in_sizes, int n_in,
                              void* d_out, int out_size, void* d_ws, size_t ws_size,
                              hipStream_t stream) {
    const float* lamb = (const float*)d_in[0];
    const float* mu   = (const float*)d_in[1];
    const float* buo  = (const float*)d_in[2];
    const float* amps = (const float*)d_in[3];
    const int*   sloc = (const int*)d_in[4];
    const int*   rloc = (const int*)d_in[5];
    float* out = (float*)d_out;

    float* wsf = (float*)d_ws;
    // layout: [strips: 12*FSTRIDE ull (2 parities x 2 shots x 3 fields)]
    //         [params 4*FSTRIDE f32][bdec 680 f32]
    ull*   strips = (ull*)wsf;
    float* params = wsf + (size_t)24 * FSTRIDE;
    float* bdec   = wsf + (size_t)28 * FSTRIDE;
    size_t needed = ((size_t)28 * FSTRIDE + NYP + NXP) * sizeof(float);

    dim3 pib(256, 1, 1), pig((NXP + 255) / 256, NYP, 1);

    if (ws_size >= needed) {
        (void)hipMemsetAsync(strips, 0, (size_t)12 * FSTRIDE * sizeof(ull), stream);
        init_params_kernel<<<pig, pib, 0, stream>>>(lamb, mu, buo, params);
        init_decay_kernel<<<(NYP + NXP + 255) / 256, 256, 0, stream>>>(bdec);
        void* args[] = {&strips, &params, &bdec, &amps, &sloc, &rloc, &out};
        (void)hipLaunchCooperativeKernel((void*)persist4_kernel, dim3(NSHOT * TX * TY),
                                         dim3(256), args, 0, stream);
    } else {
        float* statef = wsf + 64;
        float* paramf = wsf + 64 + (size_t)26 * FSTRIDE;
        float* bdecf  = wsf + 64 + (size_t)30 * FSTRIDE;
        (void)hipMemsetAsync(statef, 0, (size_t)26 * FSTRIDE * sizeof(float), stream);
        init_params_kernel<<<pig, pib, 0, stream>>>(lamb, mu, buo, paramf);
        init_decay_kernel<<<(NYP + NXP + 255) / 256, 256, 0, stream>>>(bdecf);
        dim3 blk(64, 4, 1), grd((NXP + 63) / 64, NYP / 4, NSHOT);
        for (int t = 0; t < NT; ++t) {
            vel_kernel<<<grd, blk, 0, stream>>>(statef, paramf, bdecf, amps, sloc, t);
            str_kernel<<<grd, blk, 0, stream>>>(statef, paramf, bdecf, rloc, out, t);
        }
    }
}

// Round 9
// 893.833 us; speedup vs baseline: 6.9206x; 1.1624x over previous
//
#include <hip/hip_runtime.h>

// ---------------------------------------------------------------------------
// Elastic 2D velocity-stress staggered FD + C-PML, 2 shots, 128 steps.
// Round 9: R7 (proven) + two minimal latency fixes in the halo pull:
//  (a) 3 stress fields interleaved per cell (ull[4] record, 32B-aligned) so
//      one cell's pulls hit ONE 64B cache line (3 round trips -> ~1);
//  (b) per-cell batched issue: load all 3 fields back-to-back, then tag-check.
// Everything else is verbatim R7: tag-in-data 8B relaxed agent atomics,
// parity double-buffered strips, +2 redundant velocity ring, no fences.
// ---------------------------------------------------------------------------

typedef unsigned long long ull;

#define NYI   300
#define NXI   300
#define PML   20
#define NYP   340
#define NXP   340
#define NT    128
#define DXC   5.0f
#define DTC   0.001f
#define NSHOT 2
#define NREC  32
#define C1C   (9.0f / 8.0f)
#define C2C   (-1.0f / 24.0f)
#define RDX   (1.0f / 5.0f)

#define PITCH   344
#define FSTRIDE (NYP * PITCH)

// tile grid per shot: 8 x 16 tiles
#define TX 8
#define TY 16
#define TW 43
#define TH 22
#define MH 30
#define MW 52
#define VH 26
#define VW 48
#define IH 22
#define IW 44

__device__ __forceinline__ ull aload(const ull* p) {
    return __hip_atomic_load(p, __ATOMIC_RELAXED, __HIP_MEMORY_SCOPE_AGENT);
}
__device__ __forceinline__ void pushv(ull* p, float v, unsigned tag) {
    ull u = ((ull)tag << 32) | (ull)__float_as_uint(v);
    __hip_atomic_store(p, u, __ATOMIC_RELAXED, __HIP_MEMORY_SCOPE_AGENT);
}

__global__ void init_params_kernel(const float* __restrict__ lamb,
                                   const float* __restrict__ mu,
                                   const float* __restrict__ buo,
                                   float* __restrict__ params) {
    int x = blockIdx.x * blockDim.x + threadIdx.x;
    int y = blockIdx.y;
    if (x >= NXP || y >= NYP) return;
    int cy = y - PML; cy = cy < 0 ? 0 : (cy > NYI - 1 ? NYI - 1 : cy);
    int cx = x - PML; cx = cx < 0 ? 0 : (cx > NXI - 1 ? NXI - 1 : cx);
    float l = lamb[cy * NXI + cx];
    float m = mu[cy * NXI + cx];
    float b = buo[cy * NXI + cx];
    int idx = y * PITCH + x;
    params[0 * FSTRIDE + idx] = l;
    params[1 * FSTRIDE + idx] = l + 2.0f * m;
    params[2 * FSTRIDE + idx] = m;
    params[3 * FSTRIDE + idx] = b;
}

__global__ void init_decay_kernel(float* __restrict__ bdec) {
    int i = blockIdx.x * blockDim.x + threadIdx.x;
    if (i >= NYP + NXP) return;
    int idx = (i < NYP) ? i : i - NYP;
    float fx = (float)idx;
    float lo = fminf(fmaxf(((float)PML - fx) / (float)PML, 0.0f), 1.0f);
    float hi = fminf(fmaxf((fx - (float)(NYP - 1 - PML)) / (float)PML, 0.0f), 1.0f);
    float mx = fmaxf(lo, hi);
    float d0 = 3.0f * 2000.0f / (2.0f * (float)PML * DXC) * logf(1.0f / 1e-6f);
    bdec[i] = expf(-d0 * mx * mx * DTC);
}

__global__ __launch_bounds__(256)
void persist6_kernel(ull* __restrict__ strips, const float* __restrict__ params,
                     const float* __restrict__ bdec, const float* __restrict__ amps,
                     const int* __restrict__ sloc, const int* __restrict__ rloc,
                     float* __restrict__ out) {
    __shared__ float syyR[MH][MW], sxxR[MH][MW], sxyR[MH][MW];
    __shared__ float vyR[VH][VW], vxR[VH][VW];
    __shared__ float mv0[VH][VW], mv1[VH][VW], mv2[VH][VW], mv3[VH][VW];
    __shared__ float ms0[IH][IW], ms1[IH][IW], ms2[IH][IW], ms3[IH][IW];
    __shared__ float buoL[VH][VW];
    __shared__ float lamL[IH][IW], lp2mL[IH][IW], muL[IH][IW];
    __shared__ float byL[VH], bxL[VW];

    const int tid = threadIdx.x;
    const int s = blockIdx.x >> 7, tile = blockIdx.x & 127;
    const int txi = tile & 7, tyi = tile >> 3;
    const int x0 = txi * TW, x1 = min(x0 + TW, NXP);
    const int y0 = tyi * TH, y1 = min(y0 + TH, NYP);
    const int w = x1 - x0, h = y1 - y0;

    // ---- zero LDS state; load params/decay into LDS ----
    for (int i = tid; i < MH * MW; i += 256) {
        int r = i / MW, c = i - r * MW;
        syyR[r][c] = 0.0f; sxxR[r][c] = 0.0f; sxyR[r][c] = 0.0f;
    }
    for (int i = tid; i < VH * VW; i += 256) {
        int r = i / VW, c = i - r * VW;
        vyR[r][c] = 0.0f; vxR[r][c] = 0.0f;
        mv0[r][c] = 0.0f; mv1[r][c] = 0.0f; mv2[r][c] = 0.0f; mv3[r][c] = 0.0f;
        buoL[r][c] = 0.0f;
    }
    for (int i = tid; i < IH * IW; i += 256) {
        int r = i / IW, c = i - r * IW;
        ms0[r][c] = 0.0f; ms1[r][c] = 0.0f; ms2[r][c] = 0.0f; ms3[r][c] = 0.0f;
    }
    if (tid < VH) {
        int y = y0 - 2 + tid; y = min(max(y, 0), NYP - 1);
        byL[tid] = bdec[y];
    } else if (tid >= 64 && tid < 64 + VW) {
        int i = tid - 64, x = x0 - 2 + i; x = min(max(x, 0), NXP - 1);
        bxL[i] = bdec[NYP + x];
    }
    __syncthreads();
    {
        int ry0v = max(y0 - 2, 0), ry1v = min(y1 + 2, NYP);
        int rx0v = max(x0 - 2, 0), rx1v = min(x1 + 2, NXP);
        int rh = ry1v - ry0v, rw = rx1v - rx0v;
        for (int i = tid; i < rh * rw; i += 256) {
            int r = i / rw, c = i - r * rw;
            int y = ry0v + r, x = rx0v + c;
            buoL[y - y0 + 2][x - x0 + 2] = params[3 * FSTRIDE + y * PITCH + x];
        }
        for (int i = tid; i < h * w; i += 256) {
            int r = i / w, c = i - r * w;
            int gi = (y0 + r) * PITCH + (x0 + c);
            lamL[r][c] = params[gi];
            lp2mL[r][c] = params[FSTRIDE + gi];
            muL[r][c] = params[2 * FSTRIDE + gi];
        }
    }

    const int sy = sloc[s * 2 + 0] + PML;
    const int sx = sloc[s * 2 + 1] + PML;

    bool hasRec = false; int recOff = 0, rvi = 0, rvj = 0;
    if (tid < NSHOT * NREC) {
        int rs = tid >> 5, rr = tid & 31;
        if (rs == s) {
            int ry = rloc[(rs * NREC + rr) * 2 + 0] + PML;
            int rx = rloc[(rs * NREC + rr) * 2 + 1] + PML;
            if (ry >= y0 && ry < y1 && rx >= x0 && rx < x1) {
                hasRec = true; recOff = (rs * NREC + rr) * NT;
                rvi = ry - y0 + 2; rvj = rx - x0 + 2;
            }
        }
    }
    __syncthreads();

    // region geometry (identical to R6/R7, validated)
    const int vy0 = max(y0 - 2, 0), vy1 = min(y1 + 2, NYP);
    const int vx0 = max(x0 - 2, 0), vx1 = min(x1 + 2, NXP);
    const int cy0 = y0 + 2, cy1 = y1 - 2, cx0 = x0 + 2, cx1 = x1 - 2;
    const int cw = cx1 - cx0, ch = cy1 - cy0, nCore = cw * ch;
    const int W2 = vx1 - vx0;
    const int topH = cy0 - vy0, botH = vy1 - cy1;
    const int leftW = cx0 - vx0, rightW = vx1 - cx1;
    const int nTop = topH * W2, nBot = botH * W2;
    const int nLeft = ch * leftW, nRight = ch * rightW;
    const int nRing = nTop + nBot + nLeft + nRight;
    const int py0 = max(y0 - 4, 0), py1 = min(y1 + 4, NYP);
    const int px0 = max(x0 - 4, 0), px1 = min(x1 + 4, NXP);
    const int W4 = px1 - px0;
    const int ptH = y0 - py0, pbH = py1 - y1;
    const int plW = x0 - px0, prW = px1 - x1;
    const int nPT = ptH * W4, nPB = pbH * W4, nPL = h * plW, nPR = h * prW;
    const int nPull = nPT + nPB + nPL + nPR;

    auto doV = [&](int y, int x, float amp) {
        int hy = y - y0 + 4, hx = x - x0 + 4;
        int vi = y - y0 + 2, vj = x - x0 + 2;
        float by = byL[vi], bx = bxL[vj];
        float d1 = (C1C * (syyR[hy + 1][hx] - syyR[hy][hx]) +
                    C2C * (syyR[hy + 2][hx] - syyR[hy - 1][hx])) * RDX;   // dpy(syy)
        float m1 = by * mv0[vi][vj] + (by - 1.0f) * d1; mv0[vi][vj] = m1;
        float d2 = (C1C * (sxyR[hy][hx] - sxyR[hy][hx - 1]) +
                    C2C * (sxyR[hy][hx + 1] - sxyR[hy][hx - 2])) * RDX;   // dmx(sxy)
        float m2 = bx * mv1[vi][vj] + (bx - 1.0f) * d2; mv1[vi][vj] = m2;
        float nvy = vyR[vi][vj] + DTC * buoL[vi][vj] * (d1 + m1 + d2 + m2);
        float d3 = (C1C * (sxyR[hy][hx] - sxyR[hy - 1][hx]) +
                    C2C * (sxyR[hy + 1][hx] - sxyR[hy - 2][hx])) * RDX;   // dmy(sxy)
        float m3 = by * mv2[vi][vj] + (by - 1.0f) * d3; mv2[vi][vj] = m3;
        float d4 = (C1C * (sxxR[hy][hx + 1] - sxxR[hy][hx]) +
                    C2C * (sxxR[hy][hx + 2] - sxxR[hy][hx - 1])) * RDX;   // dpx(sxx)
        float m4 = bx * mv3[vi][vj] + (bx - 1.0f) * d4; mv3[vi][vj] = m4;
        float nvx = vxR[vi][vj] + DTC * buoL[vi][vj] * (d3 + m3 + d4 + m4);
        if (y == sy && x == sx) nvy += amp;
        vyR[vi][vj] = nvy; vxR[vi][vj] = nvx;
    };

    auto doS = [&](int ly, int lx, ull* q, unsigned tag, bool pub) {
        int vi = ly + 2, vj = lx + 2;
        float by = byL[vi], bx = bxL[vj];
        float d, m;
        d = (C1C * (vyR[vi][vj] - vyR[vi - 1][vj]) +
             C2C * (vyR[vi + 1][vj] - vyR[vi - 2][vj])) * RDX;            // dmy(vy)
        m = by * ms0[ly][lx] + (by - 1.0f) * d; ms0[ly][lx] = m;
        float dvy_dy = d + m;
        d = (C1C * (vxR[vi][vj] - vxR[vi][vj - 1]) +
             C2C * (vxR[vi][vj + 1] - vxR[vi][vj - 2])) * RDX;            // dmx(vx)
        m = bx * ms1[ly][lx] + (bx - 1.0f) * d; ms1[ly][lx] = m;
        float dvx_dx = d + m;
        float nsyy = syyR[ly + 4][lx + 4] + DTC * (lp2mL[ly][lx] * dvy_dy + lamL[ly][lx] * dvx_dx);
        float nsxx = sxxR[ly + 4][lx + 4] + DTC * (lp2mL[ly][lx] * dvx_dx + lamL[ly][lx] * dvy_dy);
        d = (C1C * (vyR[vi][vj + 1] - vyR[vi][vj]) +
             C2C * (vyR[vi][vj + 2] - vyR[vi][vj - 1])) * RDX;            // dpx(vy)
        m = bx * ms2[ly][lx] + (bx - 1.0f) * d; ms2[ly][lx] = m;
        float dvy_dx = d + m;
        d = (C1C * (vxR[vi + 1][vj] - vxR[vi][vj]) +
             C2C * (vxR[vi + 2][vj] - vxR[vi - 1][vj])) * RDX;            // dpy(vx)
        m = by * ms3[ly][lx] + (by - 1.0f) * d; ms3[ly][lx] = m;
        float dvx_dy = d + m;
        float nsxy = sxyR[ly + 4][lx + 4] + DTC * muL[ly][lx] * (dvy_dx + dvx_dy);
        syyR[ly + 4][lx + 4] = nsyy;
        sxxR[ly + 4][lx + 4] = nsxx;
        sxyR[ly + 4][lx + 4] = nsxy;
        if (pub) {
            int gi = (y0 + ly) * PITCH + (x0 + lx);
            ull* c = q + (size_t)gi * 4;
            pushv(c, nsyy, tag);
            pushv(c + 1, nsxx, tag);
            pushv(c + 2, nsxy, tag);
        }
    };

    for (int t = 0; t < NT; ++t) {
        const float amp_t = amps[s * NT + t];

        // ---- A: velocity core (block-local) ----
        for (int i = tid; i < nCore; i += 256) {
            int r = i / cw, c = i - r * cw;
            doV(cy0 + r, cx0 + c, amp_t);
        }

        // ---- B: pull stress halo; per cell the 3 field words share one
        //      64B line (interleaved layout) and are issued before any check ----
        {
            const ull* bb = strips + (size_t)(((t ^ 1) & 1) * NSHOT + s) * 4 * FSTRIDE;
            const unsigned want = (unsigned)t;
            for (int i = tid; i < nPull; i += 256) {
                int y, x, j = i;
                if (j < nPT)            { y = py0 + j / W4;  x = px0 + j % W4; }
                else { j -= nPT;
                if (j < nPB)            { y = y1 + j / W4;   x = px0 + j % W4; }
                else { j -= nPB;
                if (j < nPL)            { y = y0 + j / plW;  x = px0 + j % plW; }
                else { j -= nPL;          y = y0 + j / prW;  x = x1 + j % prW; } } }
                int gi = y * PITCH + x;
                int hy = y - y0 + 4, hx = x - x0 + 4;
                const ull* c = bb + (size_t)gi * 4;
                ull ua = aload(c);
                ull ub = aload(c + 1);
                ull uc = aload(c + 2);
                while ((unsigned)(ua >> 32) != want) {
                    __builtin_amdgcn_s_sleep(1); ua = aload(c);
                }
                syyR[hy][hx] = __uint_as_float((unsigned)ua);
                while ((unsigned)(ub >> 32) != want) {
                    __builtin_amdgcn_s_sleep(1); ub = aload(c + 1);
                }
                sxxR[hy][hx] = __uint_as_float((unsigned)ub);
                while ((unsigned)(uc >> 32) != want) {
                    __builtin_amdgcn_s_sleep(1); uc = aload(c + 2);
                }
                sxyR[hy][hx] = __uint_as_float((unsigned)uc);
            }
        }
        __syncthreads();

        // ---- C: velocity ring (+2 redundant, needs the pulled halo) ----
        for (int i = tid; i < nRing; i += 256) {
            int y, x, j = i;
            if (j < nTop)           { y = vy0 + j / W2;     x = vx0 + j % W2; }
            else { j -= nTop;
            if (j < nBot)           { y = cy1 + j / W2;     x = vx0 + j % W2; }
            else { j -= nBot;
            if (j < nLeft)          { y = cy0 + j / leftW;  x = vx0 + j % leftW; }
            else { j -= nLeft;        y = cy0 + j / rightW; x = cx1 + j % rightW; } } }
            doV(y, x, amp_t);
        }
        __syncthreads();

        if (hasRec) out[recOff + t] = vyR[rvi][rvj];

        // ---- D1: boundary stress (depth<4), publish immediately (tag t+1) ----
        {
            ull* pb = strips + (size_t)((t & 1) * NSHOT + s) * 4 * FSTRIDE;
            const unsigned tag = (unsigned)(t + 1);
            const int midH = h - 8;
            const int nT4 = 4 * w, nB4 = 4 * w, nL4 = midH * 4;
            const int nD1 = nT4 + nB4 + 2 * nL4;
            for (int i = tid; i < nD1; i += 256) {
                int ly, lx, j = i;
                if (j < nT4)      { ly = j / w;           lx = j - (j / w) * w; }
                else { j -= nT4;
                if (j < nB4)      { ly = h - 4 + j / w;   lx = j - (j / w) * w; }
                else { j -= nB4;
                if (j < nL4)      { ly = 4 + (j >> 2);    lx = j & 3; }
                else { j -= nL4;    ly = 4 + (j >> 2);    lx = w - 4 + (j & 3); } } }
                doS(ly, lx, pb, tag, true);
            }
            // ---- D2: interior stress (off the inter-block critical path) ----
            const int w8 = w - 8, nD2 = midH * w8;
            for (int i = tid; i < nD2; i += 256) {
                int r = i / w8, c = i - r * w8;
                doS(4 + r, 4 + c, pb, 0u, false);
            }
        }
        __syncthreads();
    }
}

// ------------------------------ fallback path (R1, proven) ------------------

__global__ __launch_bounds__(256)
void vel_kernel(float* __restrict__ ws, const float* __restrict__ params,
                const float* __restrict__ bdec, const float* __restrict__ amps,
                const int* __restrict__ sloc, int t) {
    int x = blockIdx.x * 64 + threadIdx.x;
    int y = blockIdx.y * 4 + threadIdx.y;
    int s = blockIdx.z;
    if (x >= NXP) return;
    float* F = ws + (size_t)s * 13 * FSTRIDE;
    float* vy = F; float* vx = F + FSTRIDE;
    const float* syy = F + 2 * FSTRIDE;
    const float* sxx = F + 3 * FSTRIDE;
    const float* sxy = F + 4 * FSTRIDE;
    float* msyy_y = F + 9 * FSTRIDE;  float* msxy_x = F + 10 * FSTRIDE;
    float* msxy_y = F + 11 * FSTRIDE; float* msxx_x = F + 12 * FSTRIDE;
    float by = bdec[y], bx = bdec[NYP + x];
    int idx = y * PITCH + x;
    auto ldf2 = [&](const float* f, int yy, int xx) {
        return (yy >= 0 && yy < NYP && xx >= 0 && xx < NXP) ? f[yy * PITCH + xx] : 0.0f;
    };
    float buoy = params[3 * FSTRIDE + idx];
    float d, m;
    d = (C1C * (ldf2(syy,y+1,x) - ldf2(syy,y,x)) + C2C * (ldf2(syy,y+2,x) - ldf2(syy,y-1,x))) * RDX;
    m = by * msyy_y[idx] + (by - 1.0f) * d; msyy_y[idx] = m;
    float a1 = d + m;
    d = (C1C * (ldf2(sxy,y,x) - ldf2(sxy,y,x-1)) + C2C * (ldf2(sxy,y,x+1) - ldf2(sxy,y,x-2))) * RDX;
    m = bx * msxy_x[idx] + (bx - 1.0f) * d; msxy_x[idx] = m;
    float nvy = vy[idx] + DTC * buoy * (a1 + d + m);
    d = (C1C * (ldf2(sxy,y,x) - ldf2(sxy,y-1,x)) + C2C * (ldf2(sxy,y+1,x) - ldf2(sxy,y-2,x))) * RDX;
    m = by * msxy_y[idx] + (by - 1.0f) * d; msxy_y[idx] = m;
    float a2 = d + m;
    d = (C1C * (ldf2(sxx,y,x+1) - ldf2(sxx,y,x)) + C2C * (ldf2(sxx,y,x+2) - ldf2(sxx,y,x-1))) * RDX;
    m = bx * msxx_x[idx] + (bx - 1.0f) * d; msxx_x[idx] = m;
    float nvx = vx[idx] + DTC * buoy * (a2 + d + m);
    int sy = sloc[s * 2 + 0] + PML, sx = sloc[s * 2 + 1] + PML;
    if (y == sy && x == sx) nvy += amps[s * NT + t];
    vy[idx] = nvy; vx[idx] = nvx;
}

__global__ __launch_bounds__(256)
void str_kernel(float* __restrict__ ws, const float* __restrict__ params,
                const float* __restrict__ bdec, const int* __restrict__ rloc,
                float* __restrict__ out, int t) {
    int x = blockIdx.x * 64 + threadIdx.x;
    int y = blockIdx.y * 4 + threadIdx.y;
    int s = blockIdx.z;
    float* F = ws + (size_t)s * 13 * FSTRIDE;
    const float* vy = F; const float* vx = F + FSTRIDE;
    float* syy = F + 2 * FSTRIDE; float* sxx = F + 3 * FSTRIDE; float* sxy = F + 4 * FSTRIDE;
    float* mvyy = F + 5 * FSTRIDE; float* mvyx = F + 6 * FSTRIDE;
    float* mvxy = F + 7 * FSTRIDE; float* mvxx = F + 8 * FSTRIDE;
    if (blockIdx.x == 0 && blockIdx.y == 0) {
        int tid = threadIdx.y * 64 + threadIdx.x;
        if (tid < NREC) {
            int ry = rloc[(s * NREC + tid) * 2 + 0] + PML;
            int rx = rloc[(s * NREC + tid) * 2 + 1] + PML;
            out[(s * NREC + tid) * NT + t] = vy[ry * PITCH + rx];
        }
    }
    if (x >= NXP) return;
    auto ldf2 = [&](const float* f, int yy, int xx) {
        return (yy >= 0 && yy < NYP && xx >= 0 && xx < NXP) ? f[yy * PITCH + xx] : 0.0f;
    };
    float by = bdec[y], bx = bdec[NYP + x];
    int idx = y * PITCH + x;
    float lam = params[idx], lp2m = params[FSTRIDE + idx], muv = params[2 * FSTRIDE + idx];
    float d, m;
    d = (C1C * (ldf2(vy,y,x) - ldf2(vy,y-1,x)) + C2C * (ldf2(vy,y+1,x) - ldf2(vy,y-2,x))) * RDX;
    m = by * mvyy[idx] + (by - 1.0f) * d; mvyy[idx] = m;
    float dvy_dy = d + m;
    d = (C1C * (ldf2(vx,y,x) - ldf2(vx,y,x-1)) + C2C * (ldf2(vx,y,x+1) - ldf2(vx,y,x-2))) * RDX;
    m = bx * mvxx[idx] + (bx - 1.0f) * d; mvxx[idx] = m;
    float dvx_dx = d + m;
    syy[idx] += DTC * (lp2m * dvy_dy + lam * dvx_dx);
    sxx[idx] += DTC * (lp2m * dvx_dx + lam * dvy_dy);
    d = (C1C * (ldf2(vy,y,x+1) - ldf2(vy,y,x)) + C2C * (ldf2(vy,y,x+2) - ldf2(vy,y,x-1))) * RDX;
    m = bx * mvyx[idx] + (bx - 1.0f) * d; mvyx[idx] = m;
    float dvy_dx = d + m;
    d = (C1C * (ldf2(vx,y+1,x) - ldf2(vx,y,x)) + C2C * (ldf2(vx,y+2,x) - ldf2(vx,y-1,x))) * RDX;
    m = by * mvxy[idx] + (by - 1.0f) * d; mvxy[idx] = m;
    float dvx_dy = d + m;
    sxy[idx] += DTC * muv * (dvy_dx + dvx_dy);
}

// ----------------------------------------------------------------------------

extern "C" void kernel_launch(void* const* d_in, const int* in_sizes, int n_in,
                              void* d_out, int out_size, void* d_ws, size_t ws_size,
                              hipStream_t stream) {
    const float* lamb = (const float*)d_in[0];
    const float* mu   = (const float*)d_in[1];
    const float* buo  = (const float*)d_in[2];
    const float* amps = (const float*)d_in[3];
    const int*   sloc = (const int*)d_in[4];
    const int*   rloc = (const int*)d_in[5];
    float* out = (float*)d_out;

    float* wsf = (float*)d_ws;
    // layout: [strips: 16*FSTRIDE ull (2 parities x 2 shots x 4-ull cell records)]
    //         [params 4*FSTRIDE f32][bdec 680 f32]
    ull*   strips = (ull*)wsf;
    float* params = wsf + (size_t)32 * FSTRIDE;
    float* bdec   = wsf + (size_t)36 * FSTRIDE;
    size_t needed = ((size_t)36 * FSTRIDE + NYP + NXP) * sizeof(float);

    dim3 pib(256, 1, 1), pig((NXP + 255) / 256, NYP, 1);

    if (ws_size >= needed) {
        (void)hipMemsetAsync(strips, 0, (size_t)16 * FSTRIDE * sizeof(ull), stream);
        init_params_kernel<<<pig, pib, 0, stream>>>(lamb, mu, buo, params);
        init_decay_kernel<<<(NYP + NXP + 255) / 256, 256, 0, stream>>>(bdec);
        void* args[] = {&strips, &params, &bdec, &amps, &sloc, &rloc, &out};
        (void)hipLaunchCooperativeKernel((void*)persist6_kernel, dim3(NSHOT * TX * TY),
                                         dim3(256), args, 0, stream);
    } else {
        float* statef = wsf + 64;
        float* paramf = wsf + 64 + (size_t)26 * FSTRIDE;
        float* bdecf  = wsf + 64 + (size_t)30 * FSTRIDE;
        (void)hipMemsetAsync(statef, 0, (size_t)26 * FSTRIDE * sizeof(float), stream);
        init_params_kernel<<<pig, pib, 0, stream>>>(lamb, mu, buo, paramf);
        init_decay_kernel<<<(NYP + NXP + 255) / 256, 256, 0, stream>>>(bdecf);
        dim3 blk(64, 4, 1), grd((NXP + 63) / 64, NYP / 4, NSHOT);
        for (int t = 0; t < NT; ++t) {
            vel_kernel<<<grd, blk, 0, stream>>>(statef, paramf, bdecf, amps, sloc, t);
            str_kernel<<<grd, blk, 0, stream>>>(statef, paramf, bdecf, rloc, out, t);
        }
    }
}